// Round 9
// baseline (7303.488 us; speedup 1.0000x reference)
//
#include <hip/hip_runtime.h>
#include <math.h>

#define N_PTS 16384
#define N_CLUSTERS 4096
#define KNN_K 16
#define C_IN 64
#define C_OUT 128
#define FAN_IN 67
#define N_ROWS (N_CLUSTERS * KNN_K)   // 65536
#define NBINS 256

typedef float vf2 __attribute__((ext_vector_type(2)));
typedef unsigned long long u64;
typedef u64 u64x2 __attribute__((ext_vector_type(2)));

// ---------------------------------------------------------------------------
// init: pp[i] = |pos_i|^2 (reference op order, no FMA), zero colsum/colsumsq
// ---------------------------------------------------------------------------
__global__ void init_kernel(const float* __restrict__ pos, float* __restrict__ pp,
                            float* __restrict__ cz) {
#pragma clang fp contract(off)
    int i = blockIdx.x * 256 + threadIdx.x;
    if (i < N_PTS) {
        float a = pos[i * 3 + 0], b = pos[i * 3 + 1], c = pos[i * 3 + 2];
        pp[i] = ((a * a) + (b * b)) + (c * c);
    }
    if (blockIdx.x == 0 && threadIdx.x < 256) cz[threadIdx.x] = 0.0f;
}

// ---------------------------------------------------------------------------
// FPS v12: v10 exactly (x-slab partition + single-barrier keyed reduce,
// proven 4499us; v11's octants REGRESSED: corner-at-the-mean pathology
// activated ~1.5x more waves) + INTRA-WAVE CHUNK PRUNING:
//   - the wave's 16 register-pairs are x-sub-slabs (slots are bin-sorted;
//     chunk c = register pairs {2c,2c+1} = 256 consecutive slots).  At setup
//     each chunk's EXACT x-interval [clo_c, chi_c] is reduced from the
//     wave's own registers and parked in SGPRs (readfirstlane) -- zero VGPR
//     pressure, and the per-chunk test is a wave-uniform s_cbranch.
//   - per step, an ACTIVE wave updates only chunks with fl(dmc^2) < wm;
//     skipped chunks are provably identity (same monotone-rounding proof as
//     the slab test, per chunk: d_p >= fl(dx_p^2) >= fl(dmc^2) >= wm >= md_p)
//     and contribute their unchanged mdv to bm with 2 max ops.
//   - recovery scans all 16 pairs (skipped chunks' mdv still valid) and the
//     u64 key/DPP/publish path is v10 verbatim -> bit-exact winner sequence.
// Update math unchanged: d=((dx*dx)+(dy*dy))+(dz*dz), no FMA (contract off),
// fmin/fmax/select only -> bit-exact vs reference.
// ---------------------------------------------------------------------------
__global__ __launch_bounds__(512)
__attribute__((amdgpu_waves_per_eu(2, 2)))
void fps_kernel(const float* __restrict__ pos, int* __restrict__ clusters) {
#pragma clang fp contract(off)
    __shared__ unsigned short s_perm[N_PTS];     // 32KB: slot -> original index
    __shared__ int s_cluster[N_CLUSTERS];        // 16KB result accumulator
    __shared__ int s_hist[NBINS];                // histogram -> ticket base
    __shared__ float s_red[16];                  // setup reduce scratch
    __shared__ __align__(16) u64 s_wkey[2][8];   // parity-buffered wave keys
    const int t = threadIdx.x;
    const int w = t >> 6, lane = t & 63;
    const int wbase = w << 11;                   // wave owns slots [w*2048,+2048)

    // ---- setup pass 0: global x min/max ----
    float txmin = __builtin_inff(), txmax = -__builtin_inff();
#pragma unroll
    for (int k = 0; k < 32; ++k) {
        const float xv = pos[(t + (k << 9)) * 3];
        txmin = fminf(txmin, xv);
        txmax = fmaxf(txmax, xv);
    }
#pragma unroll
    for (int off = 32; off >= 1; off >>= 1) {
        txmin = fminf(txmin, __shfl_xor(txmin, off));
        txmax = fmaxf(txmax, __shfl_xor(txmax, off));
    }
    if (lane == 0) { s_red[w] = txmin; s_red[8 + w] = txmax; }
    if (t < NBINS) s_hist[t] = 0;
    if (t == 0) s_cluster[0] = 0;
    __syncthreads();
    float gxmin = s_red[0], gxmax = s_red[8];
#pragma unroll
    for (int i = 1; i < 8; ++i) {
        gxmin = fminf(gxmin, s_red[i]);
        gxmax = fmaxf(gxmax, s_red[8 + i]);
    }
    const float binv = (float)NBINS / (gxmax - gxmin);

    // ---- setup pass 1: histogram ----
#pragma unroll
    for (int k = 0; k < 32; ++k) {
        const int i = t + (k << 9);
        int b = (int)((pos[i * 3] - gxmin) * binv);
        b = (b < 0) ? 0 : ((b > NBINS - 1) ? NBINS - 1 : b);
        atomicAdd(&s_hist[b], 1);
    }
    __syncthreads();
    if (t == 0) {   // serial prefix sum (one-time)
        int run = 0;
        for (int b = 0; b < NBINS; ++b) {
            const int c = s_hist[b];
            s_hist[b] = run;
            run += c;
        }
    }
    __syncthreads();
    // ---- setup pass 2: placement (bijective by tickets) ----
#pragma unroll
    for (int k = 0; k < 32; ++k) {
        const int i = t + (k << 9);
        int b = (int)((pos[i * 3] - gxmin) * binv);
        b = (b < 0) ? 0 : ((b > NBINS - 1) ? NBINS - 1 : b);
        const int dest = atomicAdd(&s_hist[b], 1);
        s_perm[dest] = (unsigned short)i;
    }
    __syncthreads();

    // ---- gather coords + packed original indices ----
    vf2 ax[16], ay[16], az[16], mdv[16];
    unsigned int oid[16];
#pragma unroll
    for (int a = 0; a < 16; ++a) {
        const int s0 = wbase + (((a << 1) | 0) << 6) + lane;
        const int s1 = wbase + (((a << 1) | 1) << 6) + lane;
        const unsigned int o0 = s_perm[s0], o1 = s_perm[s1];
        oid[a] = (o1 << 16) | o0;
        ax[a] = (vf2){pos[o0 * 3 + 0], pos[o1 * 3 + 0]};
        ay[a] = (vf2){pos[o0 * 3 + 1], pos[o1 * 3 + 1]};
        az[a] = (vf2){pos[o0 * 3 + 2], pos[o1 * 3 + 2]};
        mdv[a] = (vf2){__builtin_inff(), __builtin_inff()};
    }

    // ---- per-chunk exact x-intervals (chunk c = pairs 2c,2c+1), in SGPRs ----
    float clo[8], chi[8];
#pragma unroll
    for (int c = 0; c < 8; ++c) {
        float l = fminf(fminf(ax[2 * c].x, ax[2 * c].y),
                        fminf(ax[2 * c + 1].x, ax[2 * c + 1].y));
        float h = fmaxf(fmaxf(ax[2 * c].x, ax[2 * c].y),
                        fmaxf(ax[2 * c + 1].x, ax[2 * c + 1].y));
#pragma unroll
        for (int off = 32; off >= 1; off >>= 1) {
            l = fminf(l, __shfl_xor(l, off));
            h = fmaxf(h, __shfl_xor(h, off));
        }
        clo[c] = __int_as_float(__builtin_amdgcn_readfirstlane(__float_as_int(l)));
        chi[c] = __int_as_float(__builtin_amdgcn_readfirstlane(__float_as_int(h)));
    }
    float lo = clo[0], hi = chi[0];
#pragma unroll
    for (int c = 1; c < 8; ++c) {
        lo = fminf(lo, clo[c]);
        hi = fmaxf(hi, chi[c]);
    }

    float lx = pos[0], ly = pos[1], lz = pos[2];
    u64 wkey = 0;   // lane63 holds the wave's key after each active step

// DPP pair-max on (hi_,lo_) u64 key; old=0 masked lanes never win (lo_!=0).
#define PAIR_STAGE(CTRL, RM)                                                          \
    do {                                                                              \
        unsigned int ohi = (unsigned int)__builtin_amdgcn_update_dpp(                 \
            0, (int)hi_, (CTRL), (RM), 0xF, false);                                   \
        unsigned int olo = (unsigned int)__builtin_amdgcn_update_dpp(                 \
            0, (int)lo_, (CTRL), (RM), 0xF, false);                                   \
        u64 cur = ((u64)hi_ << 32) | lo_;                                             \
        u64 oth = ((u64)ohi << 32) | olo;                                             \
        if (oth > cur) { hi_ = ohi; lo_ = olo; }                                      \
    } while (0)

// active-wave body: chunk-pruned packed update + min-orig-idx recovery + DPP.
// WMTHR: skip chunk c iff fl(dmc^2) >= WMTHR (identity-update proof above).
#define UPDATE_AND_KEY(WMTHR)                                                         \
    do {                                                                              \
        const vf2 lxv = (vf2){lx, lx}, lyv = (vf2){ly, ly}, lzv = (vf2){lz, lz};      \
        vf2 bm = (vf2){0.0f, 0.0f};                                                   \
        _Pragma("unroll")                                                             \
        for (int c = 0; c < 8; ++c) {                                                 \
            const float dmc = fmaxf(fmaxf(clo[c] - lx, lx - chi[c]), 0.0f);           \
            if (__builtin_amdgcn_readfirstlane((int)(dmc * dmc < (WMTHR)))) {         \
                _Pragma("unroll")                                                     \
                for (int q = 0; q < 2; ++q) {                                         \
                    const int a = 2 * c + q;                                          \
                    vf2 dx = ax[a] - lxv;                                             \
                    vf2 dy = ay[a] - lyv;                                             \
                    vf2 dz = az[a] - lzv;                                             \
                    vf2 d = ((dx * dx) + (dy * dy)) + (dz * dz);                      \
                    vf2 m;                                                            \
                    m.x = fminf(mdv[a].x, d.x);                                       \
                    m.y = fminf(mdv[a].y, d.y);                                       \
                    mdv[a] = m;                                                       \
                    bm = __builtin_elementwise_max(bm, m);                            \
                }                                                                     \
            } else {                                                                  \
                bm = __builtin_elementwise_max(bm, mdv[2 * c]);                       \
                bm = __builtin_elementwise_max(bm, mdv[2 * c + 1]);                   \
            }                                                                         \
        }                                                                             \
        const float bv = fmaxf(bm.x, bm.y);                                           \
        unsigned int mi = 0xffffffffu;                                                \
        _Pragma("unroll")                                                             \
        for (int a = 0; a < 16; ++a) {                                                \
            const unsigned int c0 =                                                   \
                (mdv[a].x == bv) ? (oid[a] & 0xffffu) : 0xffffffffu;                  \
            const unsigned int c1 =                                                   \
                (mdv[a].y == bv) ? (oid[a] >> 16) : 0xffffffffu;                      \
            const unsigned int cc = (c0 < c1) ? c0 : c1;                              \
            mi = (cc < mi) ? cc : mi;                                                 \
        }                                                                             \
        unsigned int hi_ = __float_as_uint(bv);                                       \
        unsigned int lo_ = ~mi;                                                       \
        PAIR_STAGE(0x111, 0xF);                                                       \
        PAIR_STAGE(0x112, 0xF);                                                       \
        PAIR_STAGE(0x114, 0xF);                                                       \
        PAIR_STAGE(0x118, 0xF);                                                       \
        PAIR_STAGE(0x142, 0xA);                                                       \
        PAIR_STAGE(0x143, 0xC);                                                       \
        wkey = ((u64)hi_ << 32) | lo_;                                                \
    } while (0)

    // ---- prologue: step-0 update vs cluster 0 (all chunks), keys -> buf[1] ----
    UPDATE_AND_KEY(__builtin_inff());
    if (lane == 63) s_wkey[1][w] = wkey;
    __syncthreads();

    for (int step = 1; step < N_CLUSTERS; ++step) {
        const int p = step & 1;
        // ---- read 8 wave keys (broadcast) + u64 max tree ----
        const u64x2* kp = (const u64x2*)&s_wkey[p][0];
        const u64x2 k0 = kp[0], k1 = kp[1], k2 = kp[2], k3 = kp[3];
        u64 b0 = (k0.x > k0.y) ? k0.x : k0.y;
        u64 b1 = (k1.x > k1.y) ? k1.x : k1.y;
        u64 b2 = (k2.x > k2.y) ? k2.x : k2.y;
        u64 b3 = (k3.x > k3.y) ? k3.x : k3.y;
        b0 = (b1 > b0) ? b1 : b0;
        b2 = (b3 > b2) ? b3 : b2;
        const u64 bkey = (b2 > b0) ? b2 : b0;
        const unsigned int win = ~((unsigned int)bkey);
        if (t == 0) s_cluster[step] = (int)win;

        // ---- uniform scalar fetch of winner coords ----
        const unsigned int winu =
            (unsigned int)__builtin_amdgcn_readfirstlane((int)win);
        lx = pos[winu * 3 + 0];
        ly = pos[winu * 3 + 1];
        lz = pos[winu * 3 + 2];

        // ---- exact slab skip test (wave-uniform; wm = own cached value) ----
        const u64 own = s_wkey[p][w];
        const float wm = __uint_as_float((unsigned int)(own >> 32));
        const float dm = fmaxf(fmaxf(lo - lx, lx - hi), 0.0f);
        const bool act = (dm * dm < wm);
        if (__builtin_amdgcn_readfirstlane((int)act)) UPDATE_AND_KEY(wm);

        // ---- publish (cached or fresh) key for the NEXT step; one barrier ----
        if (lane == 63) s_wkey[p ^ 1][w] = wkey;
        __syncthreads();
    }
#undef UPDATE_AND_KEY
#undef PAIR_STAGE

    // bulk coalesced store of the cluster list
    for (int i = t; i < N_CLUSTERS; i += 512) clusters[i] = s_cluster[i];
}

// ---------------------------------------------------------------------------
// kNN: one block per cluster, 256 threads. d = (qq+pp) - 2*dot (dot FMA-
// ascending like BLAS), LDS distance array per 8192-chunk, 16 argmin rounds
// per chunk (tie -> lower index == stable top_k), exact merge of 2x16.
// Only the neighbor SET matters downstream.
// ---------------------------------------------------------------------------
__global__ __launch_bounds__(256) void knn_kernel(const float* __restrict__ pos,
                                                  const float* __restrict__ pp,
                                                  const int* __restrict__ clusters,
                                                  int* __restrict__ nbr) {
#pragma clang fp contract(off)
    __shared__ float s_d[8192];
    __shared__ float s_rv[4];
    __shared__ int   s_ri[4];
    __shared__ float s_tv[32];
    __shared__ int   s_ti[32];
    const int m = blockIdx.x, t = threadIdx.x;
    const int lane = t & 63, w = t >> 6;

    const int qi = clusters[m];
    const float qx = pos[qi * 3 + 0], qy = pos[qi * 3 + 1], qz = pos[qi * 3 + 2];
    const float qq = ((qx * qx) + (qy * qy)) + (qz * qz);

    for (int chunk = 0; chunk < 2; ++chunk) {
        const int base = chunk << 13;
        __syncthreads();  // protect s_d overwrite vs previous chunk's reads
        for (int i = t; i < 8192; i += 256) {
            const int p = base + i;
            float dot = fmaf(qx, pos[p * 3 + 0], 0.0f);
            dot = fmaf(qy, pos[p * 3 + 1], dot);
            dot = fmaf(qz, pos[p * 3 + 2], dot);
            s_d[i] = (qq + pp[p]) - 2.0f * dot;
        }
        __syncthreads();
        for (int r = 0; r < KNN_K; ++r) {
            float bv = __builtin_inff();
            int   bi = 0x7fffffff;
            for (int i = t; i < 8192; i += 256) {   // i ascending per thread
                float v = s_d[i];
                if (v < bv) { bv = v; bi = i; }     // strict < keeps first
            }
#pragma unroll
            for (int off = 32; off >= 1; off >>= 1) {
                float ov = __shfl_down(bv, off);
                int   oi = __shfl_down(bi, off);
                if (ov < bv || (ov == bv && oi < bi)) { bv = ov; bi = oi; }
            }
            if (lane == 0) { s_rv[w] = bv; s_ri[w] = bi; }
            __syncthreads();
            if (t == 0) {
                float fv = s_rv[0]; int fi = s_ri[0];
#pragma unroll
                for (int ww = 1; ww < 4; ++ww) {
                    if (s_rv[ww] < fv || (s_rv[ww] == fv && s_ri[ww] < fi)) {
                        fv = s_rv[ww]; fi = s_ri[ww];
                    }
                }
                s_tv[chunk * 16 + r] = fv;
                s_ti[chunk * 16 + r] = base + fi;
                s_d[fi] = __builtin_inff();
            }
            __syncthreads();
        }
    }
    if (t == 0) {   // exact merge of two sorted-by-(v,idx) lists
        int a = 0, b = 0;
        for (int r = 0; r < KNN_K; ++r) {
            bool takeA;
            if (b >= 16) takeA = true;
            else if (a >= 16) takeA = false;
            else {
                float va = s_tv[a], vb = s_tv[16 + b];
                takeA = (va < vb) || (va == vb && s_ti[a] < s_ti[16 + b]);
            }
            nbr[m * KNN_K + r] = takeA ? s_ti[a] : s_ti[16 + b];
            if (takeA) ++a; else ++b;
        }
    }
}

// ---------------------------------------------------------------------------
// MLP: grouped[r] = [pos[n]-pos[r>>4] (quirky full-pos indexing!), x[n]],
// h = grouped @ W^T.  PASS 1: accumulate column sum/sumsq.  PASS 2:
// recompute, y = scale*h+shift, out[m,c] = relu(max_k y) (relu∘max=max∘relu),
// plus sub_pos / sub_batch.  64 rows (= 4 whole clusters) x 128 cols / block.
// ---------------------------------------------------------------------------
template <int PASS>
__global__ __launch_bounds__(256) void mlp_kernel(const float* __restrict__ x,
                                                  const float* __restrict__ pos,
                                                  const int* __restrict__ nbr,
                                                  const float* __restrict__ W,
                                                  float* __restrict__ colsum,
                                                  float* __restrict__ colsumsq,
                                                  const float* __restrict__ ss,
                                                  const int* __restrict__ clusters,
                                                  const int* __restrict__ batch,
                                                  float* __restrict__ out) {
    __shared__ __align__(16) float At[FAN_IN][68];     // [i][r], pad 68
    __shared__ __align__(16) float Wl[FAN_IN * 132];   // [i][c], pad 132
    __shared__ float red0[128], red1[128];
    __shared__ float hm[8][132];                       // pass2 half-cluster maxima
    const int tid = threadIdx.x;
    const int R0 = blockIdx.x * 64;

    // stage W transposed
    for (int idx = tid; idx < FAN_IN * 128; idx += 256) {
        int i = idx >> 7, c = idx & 127;
        Wl[i * 132 + c] = W[c * FAN_IN + i];
    }
    // stage A transposed (gather)
    {
        const int wv = tid >> 6, lane = tid & 63;
        for (int r = wv; r < 64; r += 4) {
            const int R = R0 + r;
            const int n = nbr[R];
            At[3 + lane][r] = x[n * C_IN + lane];
            if (lane < 3) {
                const int q = R >> 4;  // faithful to source: cluster ORDINAL indexes pos
                At[lane][r] = pos[n * 3 + lane] - pos[q * 3 + lane];
            }
        }
    }
    if (PASS == 1 && tid < 128) { red0[tid] = 0.0f; red1[tid] = 0.0f; }
    __syncthreads();

    const int g = tid & 31, rg = tid >> 5;
    const int c0 = g * 4, r0 = rg * 8;
    float acc[8][4];
#pragma unroll
    for (int a = 0; a < 8; ++a)
#pragma unroll
        for (int b = 0; b < 4; ++b) acc[a][b] = 0.0f;

    for (int i = 0; i < FAN_IN; ++i) {
        const float4 w4 = *(const float4*)&Wl[i * 132 + c0];
        const float4 a0 = *(const float4*)&At[i][r0];
        const float4 a1 = *(const float4*)&At[i][r0 + 4];
        const float av[8] = {a0.x, a0.y, a0.z, a0.w, a1.x, a1.y, a1.z, a1.w};
        const float wv4[4] = {w4.x, w4.y, w4.z, w4.w};
#pragma unroll
        for (int a = 0; a < 8; ++a)
#pragma unroll
            for (int b = 0; b < 4; ++b) acc[a][b] = fmaf(av[a], wv4[b], acc[a][b]);
    }

    if (PASS == 1) {
#pragma unroll
        for (int b = 0; b < 4; ++b) {
            float s = 0.0f, sq = 0.0f;
#pragma unroll
            for (int a = 0; a < 8; ++a) {
                s += acc[a][b];
                sq = fmaf(acc[a][b], acc[a][b], sq);
            }
            atomicAdd(&red0[c0 + b], s);
            atomicAdd(&red1[c0 + b], sq);
        }
        __syncthreads();
        if (tid < 128) {
            atomicAdd(&colsum[tid], red0[tid]);
            atomicAdd(&colsumsq[tid], red1[tid]);
        }
    } else {
        // rows r0..r0+7 lie in ONE cluster (half of it): reduce then combine
#pragma unroll
        for (int b = 0; b < 4; ++b) {
            const float sc = ss[c0 + b], sh = ss[128 + c0 + b];
            float mx = -__builtin_inff();
#pragma unroll
            for (int a = 0; a < 8; ++a) mx = fmaxf(mx, fmaf(sc, acc[a][b], sh));
            hm[rg][c0 + b] = mx;
        }
        __syncthreads();
        for (int o = tid; o < 512; o += 256) {
            const int cl = o >> 7, c = o & 127;
            const float v = fmaxf(hm[2 * cl][c], hm[2 * cl + 1][c]);
            const int M = blockIdx.x * 4 + cl;
            out[M * 128 + c] = fmaxf(v, 0.0f);
        }
        if (tid < 12) {
            const int cl = tid / 3, l = tid % 3;
            const int M = blockIdx.x * 4 + cl;
            out[524288 + M * 3 + l] = pos[clusters[M] * 3 + l];
        } else if (tid < 16) {
            const int M = blockIdx.x * 4 + (tid - 12);
            out[536576 + M] = (float)batch[clusters[M]];
        }
    }
}

// ---------------------------------------------------------------------------
// stats: scale/shift from column sums (biased var, like torch BN training)
// ---------------------------------------------------------------------------
__global__ void stats_kernel(const float* __restrict__ colsum,
                             const float* __restrict__ colsumsq,
                             const float* __restrict__ gamma,
                             const float* __restrict__ beta,
                             float* __restrict__ ss) {
    const int c = threadIdx.x;
    const float inv_n = 1.0f / (float)N_ROWS;
    const float mean = colsum[c] * inv_n;
    float var = colsumsq[c] * inv_n - mean * mean;
    var = fmaxf(var, 0.0f);
    const float inv = rsqrtf(var + 1e-5f);
    const float sc = gamma[c] * inv;
    ss[c] = sc;
    ss[128 + c] = beta[c] - mean * sc;
}

// ---------------------------------------------------------------------------
extern "C" void kernel_launch(void* const* d_in, const int* in_sizes, int n_in,
                              void* d_out, int out_size, void* d_ws, size_t ws_size,
                              hipStream_t stream) {
    const float* x     = (const float*)d_in[0];
    const float* pos   = (const float*)d_in[1];
    const int*   batch = (const int*)d_in[2];
    const float* W     = (const float*)d_in[3];
    const float* gamma = (const float*)d_in[4];
    const float* beta  = (const float*)d_in[5];
    float* out = (float*)d_out;
    float* wsf = (float*)d_ws;

    int*   clusters = (int*)d_ws;            // [4096]
    int*   nbr      = clusters + 4096;       // [65536]
    float* pp       = wsf + 69632;           // [16384]
    float* colsum   = wsf + 86016;           // [128]
    float* colsumsq = wsf + 86144;           // [128]
    float* ss       = wsf + 86272;           // [256]

    init_kernel<<<dim3(64), dim3(256), 0, stream>>>(pos, pp, colsum);
    fps_kernel<<<dim3(1), dim3(512), 0, stream>>>(pos, clusters);
    knn_kernel<<<dim3(N_CLUSTERS), dim3(256), 0, stream>>>(pos, pp, clusters, nbr);
    mlp_kernel<1><<<dim3(1024), dim3(256), 0, stream>>>(x, pos, nbr, W, colsum, colsumsq,
                                                        ss, clusters, batch, out);
    stats_kernel<<<dim3(1), dim3(128), 0, stream>>>(colsum, colsumsq, gamma, beta, ss);
    mlp_kernel<2><<<dim3(1024), dim3(256), 0, stream>>>(x, pos, nbr, W, colsum, colsumsq,
                                                        ss, clusters, batch, out);
}

// Round 10
// 5087.283 us; speedup vs baseline: 1.4356x; 1.4356x over previous
//
#include <hip/hip_runtime.h>
#include <math.h>

#define N_PTS 16384
#define N_CLUSTERS 4096
#define KNN_K 16
#define C_IN 64
#define C_OUT 128
#define FAN_IN 67
#define N_ROWS (N_CLUSTERS * KNN_K)   // 65536
#define NBINS 256

typedef float vf2 __attribute__((ext_vector_type(2)));
typedef unsigned long long u64;
typedef u64 u64x2 __attribute__((ext_vector_type(2)));

// ---------------------------------------------------------------------------
// init: pp[i] = |pos_i|^2 (reference op order, no FMA), zero colsum/colsumsq
// ---------------------------------------------------------------------------
__global__ void init_kernel(const float* __restrict__ pos, float* __restrict__ pp,
                            float* __restrict__ cz) {
#pragma clang fp contract(off)
    int i = blockIdx.x * 256 + threadIdx.x;
    if (i < N_PTS) {
        float a = pos[i * 3 + 0], b = pos[i * 3 + 1], c = pos[i * 3 + 2];
        pp[i] = ((a * a) + (b * b)) + (c * c);
    }
    if (blockIdx.x == 0 && threadIdx.x < 256) cz[threadIdx.x] = 0.0f;
}

// ---------------------------------------------------------------------------
// FPS v13 = v10 (best verified: 4499us) + own-key-in-register.
// History: v11 octants REGRESSED (corner-at-mean put MORE waves in range);
// v12 intra-wave chunk branches REGRESSED (+1340cyc/step of s_cbranch +
// scheduling damage at 2-waves/SIMD; straight-line code wins below wave
// granularity).  v10 structure restored verbatim; one addition:
//   - after the DPP key reduce, the wave key is broadcast from lane 63 via
//     two v_readlane ops (once per ACTIVE step) so every lane carries the
//     wave's current key in registers.  The per-step skip test then reads
//     wm from the register instead of a dependent ~120cyc LDS load.
// Structure recap (all v10-proven):
//   - x-slab partition: 256-bin histogram + ticketed placement (one-time);
//     wave w owns slots [2048w, 2048w+2048) = a contiguous x-slab with
//     exact interval [lo,hi] reduced from its own registers.
//   - exact skip: dist(cx,[lo,hi])^2 >= wm  =>  update is identity for the
//     whole wave (monotone RN rounding: d_p >= fl(dx_p^2) >= fl(dm^2)).
//   - key = (f32bits(max md)<<32) | ~min_orig_idx: u64 max == (max value,
//     tie -> min ORIGINAL index) == jnp.argmax first-occurrence.
//   - single-barrier reduce: every wave publishes its (cached or fresh) key
//     to parity buffer s_wkey[(step+1)&1][w]; one barrier; all threads read
//     8 keys (4x b128 broadcast) + 7-compare u64 max tree -> winner.
//   - winner coords: uniform readfirstlane + scalar load (off VALU/LDS).
//   - cluster ids accumulate in LDS, bulk coalesced store at the end.
// Update math unchanged: d=((dx*dx)+(dy*dy))+(dz*dz), no FMA (contract off),
// fmin/fmax/select only -> bit-exact winner sequence vs reference.
// ---------------------------------------------------------------------------
__global__ __launch_bounds__(512)
__attribute__((amdgpu_waves_per_eu(2, 2)))
void fps_kernel(const float* __restrict__ pos, int* __restrict__ clusters) {
#pragma clang fp contract(off)
    __shared__ unsigned short s_perm[N_PTS];     // 32KB: slot -> original index
    __shared__ int s_cluster[N_CLUSTERS];        // 16KB result accumulator
    __shared__ int s_hist[NBINS];                // histogram -> ticket base
    __shared__ float s_red[16];                  // setup reduce scratch
    __shared__ __align__(16) u64 s_wkey[2][8];   // parity-buffered wave keys
    const int t = threadIdx.x;
    const int w = t >> 6, lane = t & 63;
    const int wbase = w << 11;                   // wave owns slots [w*2048,+2048)

    // ---- setup pass 0: global x min/max ----
    float txmin = __builtin_inff(), txmax = -__builtin_inff();
#pragma unroll
    for (int k = 0; k < 32; ++k) {
        const float xv = pos[(t + (k << 9)) * 3];
        txmin = fminf(txmin, xv);
        txmax = fmaxf(txmax, xv);
    }
#pragma unroll
    for (int off = 32; off >= 1; off >>= 1) {
        txmin = fminf(txmin, __shfl_xor(txmin, off));
        txmax = fmaxf(txmax, __shfl_xor(txmax, off));
    }
    if (lane == 0) { s_red[w] = txmin; s_red[8 + w] = txmax; }
    if (t < NBINS) s_hist[t] = 0;
    if (t == 0) s_cluster[0] = 0;
    __syncthreads();
    float gxmin = s_red[0], gxmax = s_red[8];
#pragma unroll
    for (int i = 1; i < 8; ++i) {
        gxmin = fminf(gxmin, s_red[i]);
        gxmax = fmaxf(gxmax, s_red[8 + i]);
    }
    const float binv = (float)NBINS / (gxmax - gxmin);

    // ---- setup pass 1: histogram ----
#pragma unroll
    for (int k = 0; k < 32; ++k) {
        const int i = t + (k << 9);
        int b = (int)((pos[i * 3] - gxmin) * binv);
        b = (b < 0) ? 0 : ((b > NBINS - 1) ? NBINS - 1 : b);
        atomicAdd(&s_hist[b], 1);
    }
    __syncthreads();
    if (t == 0) {   // serial prefix sum (one-time)
        int run = 0;
        for (int b = 0; b < NBINS; ++b) {
            const int c = s_hist[b];
            s_hist[b] = run;
            run += c;
        }
    }
    __syncthreads();
    // ---- setup pass 2: placement (bijective by tickets) ----
#pragma unroll
    for (int k = 0; k < 32; ++k) {
        const int i = t + (k << 9);
        int b = (int)((pos[i * 3] - gxmin) * binv);
        b = (b < 0) ? 0 : ((b > NBINS - 1) ? NBINS - 1 : b);
        const int dest = atomicAdd(&s_hist[b], 1);
        s_perm[dest] = (unsigned short)i;
    }
    __syncthreads();

    // ---- gather coords + packed original indices + exact wave x-interval ----
    vf2 ax[16], ay[16], az[16], mdv[16];
    unsigned int oid[16];
    float mnx = __builtin_inff(), mxx = -__builtin_inff();
#pragma unroll
    for (int a = 0; a < 16; ++a) {
        const int s0 = wbase + (((a << 1) | 0) << 6) + lane;
        const int s1 = wbase + (((a << 1) | 1) << 6) + lane;
        const unsigned int o0 = s_perm[s0], o1 = s_perm[s1];
        oid[a] = (o1 << 16) | o0;
        ax[a] = (vf2){pos[o0 * 3 + 0], pos[o1 * 3 + 0]};
        ay[a] = (vf2){pos[o0 * 3 + 1], pos[o1 * 3 + 1]};
        az[a] = (vf2){pos[o0 * 3 + 2], pos[o1 * 3 + 2]};
        mdv[a] = (vf2){__builtin_inff(), __builtin_inff()};
        mnx = fminf(mnx, fminf(ax[a].x, ax[a].y));
        mxx = fmaxf(mxx, fmaxf(ax[a].x, ax[a].y));
    }
#pragma unroll
    for (int off = 32; off >= 1; off >>= 1) {
        mnx = fminf(mnx, __shfl_xor(mnx, off));
        mxx = fmaxf(mxx, __shfl_xor(mxx, off));
    }
    if (lane == 0) { s_red[w] = mnx; s_red[8 + w] = mxx; }
    __syncthreads();
    const float lo = s_red[w], hi = s_red[8 + w];

    float lx = pos[0], ly = pos[1], lz = pos[2];
    u64 wkey = 0;   // ALL lanes: the wave's current key (broadcast post-DPP)

// DPP pair-max on (hi_,lo_) u64 key; old=0 masked lanes never win (lo_!=0).
#define PAIR_STAGE(CTRL, RM)                                                          \
    do {                                                                              \
        unsigned int ohi = (unsigned int)__builtin_amdgcn_update_dpp(                 \
            0, (int)hi_, (CTRL), (RM), 0xF, false);                                   \
        unsigned int olo = (unsigned int)__builtin_amdgcn_update_dpp(                 \
            0, (int)lo_, (CTRL), (RM), 0xF, false);                                   \
        u64 cur = ((u64)hi_ << 32) | lo_;                                             \
        u64 oth = ((u64)ohi << 32) | olo;                                             \
        if (oth > cur) { hi_ = ohi; lo_ = olo; }                                      \
    } while (0)

// active-wave body: packed update + min-orig-idx recovery + DPP -> wkey
// (straight-line; v12's intra-wave branches proven harmful).  Ends with a
// lane-63 broadcast so every lane carries the wave key in registers.
#define UPDATE_AND_KEY()                                                              \
    do {                                                                              \
        const vf2 lxv = (vf2){lx, lx}, lyv = (vf2){ly, ly}, lzv = (vf2){lz, lz};      \
        vf2 bm = (vf2){0.0f, 0.0f};                                                   \
        _Pragma("unroll")                                                             \
        for (int a = 0; a < 16; ++a) {                                                \
            vf2 dx = ax[a] - lxv;                                                     \
            vf2 dy = ay[a] - lyv;                                                     \
            vf2 dz = az[a] - lzv;                                                     \
            vf2 d = ((dx * dx) + (dy * dy)) + (dz * dz);                              \
            vf2 m;                                                                    \
            m.x = fminf(mdv[a].x, d.x);                                               \
            m.y = fminf(mdv[a].y, d.y);                                               \
            mdv[a] = m;                                                               \
            bm = __builtin_elementwise_max(bm, m);                                    \
        }                                                                             \
        const float bv = fmaxf(bm.x, bm.y);                                           \
        unsigned int mi = 0xffffffffu;                                                \
        _Pragma("unroll")                                                             \
        for (int a = 0; a < 16; ++a) {                                                \
            const unsigned int c0 =                                                   \
                (mdv[a].x == bv) ? (oid[a] & 0xffffu) : 0xffffffffu;                  \
            const unsigned int c1 =                                                   \
                (mdv[a].y == bv) ? (oid[a] >> 16) : 0xffffffffu;                      \
            const unsigned int cc = (c0 < c1) ? c0 : c1;                              \
            mi = (cc < mi) ? cc : mi;                                                 \
        }                                                                             \
        unsigned int hi_ = __float_as_uint(bv);                                       \
        unsigned int lo_ = ~mi;                                                       \
        PAIR_STAGE(0x111, 0xF);                                                       \
        PAIR_STAGE(0x112, 0xF);                                                       \
        PAIR_STAGE(0x114, 0xF);                                                       \
        PAIR_STAGE(0x118, 0xF);                                                       \
        PAIR_STAGE(0x142, 0xA);                                                       \
        PAIR_STAGE(0x143, 0xC);                                                       \
        hi_ = (unsigned int)__builtin_amdgcn_readlane((int)hi_, 63);                  \
        lo_ = (unsigned int)__builtin_amdgcn_readlane((int)lo_, 63);                  \
        wkey = ((u64)hi_ << 32) | lo_;                                                \
    } while (0)

    // ---- prologue: step-0 update vs cluster 0, publish keys to buf[1] ----
    UPDATE_AND_KEY();
    if (lane == 63) s_wkey[1][w] = wkey;
    __syncthreads();

    for (int step = 1; step < N_CLUSTERS; ++step) {
        const int p = step & 1;
        // ---- read 8 wave keys (broadcast) + u64 max tree ----
        const u64x2* kp = (const u64x2*)&s_wkey[p][0];
        const u64x2 k0 = kp[0], k1 = kp[1], k2 = kp[2], k3 = kp[3];
        u64 b0 = (k0.x > k0.y) ? k0.x : k0.y;
        u64 b1 = (k1.x > k1.y) ? k1.x : k1.y;
        u64 b2 = (k2.x > k2.y) ? k2.x : k2.y;
        u64 b3 = (k3.x > k3.y) ? k3.x : k3.y;
        b0 = (b1 > b0) ? b1 : b0;
        b2 = (b3 > b2) ? b3 : b2;
        const u64 bkey = (b2 > b0) ? b2 : b0;
        const unsigned int win = ~((unsigned int)bkey);
        if (t == 0) s_cluster[step] = (int)win;

        // ---- uniform scalar fetch of winner coords ----
        const unsigned int winu =
            (unsigned int)__builtin_amdgcn_readfirstlane((int)win);
        lx = pos[winu * 3 + 0];
        ly = pos[winu * 3 + 1];
        lz = pos[winu * 3 + 2];

        // ---- exact slab skip test (wm from REGISTER wkey, no LDS read) ----
        const float wm = __uint_as_float((unsigned int)(wkey >> 32));
        const float dm = fmaxf(fmaxf(lo - lx, lx - hi), 0.0f);
        const bool act = (dm * dm < wm);
        if (__builtin_amdgcn_readfirstlane((int)act)) UPDATE_AND_KEY();

        // ---- publish (cached or fresh) key for the NEXT step; one barrier ----
        if (lane == 63) s_wkey[p ^ 1][w] = wkey;
        __syncthreads();
    }
#undef UPDATE_AND_KEY
#undef PAIR_STAGE

    // bulk coalesced store of the cluster list
    for (int i = t; i < N_CLUSTERS; i += 512) clusters[i] = s_cluster[i];
}

// ---------------------------------------------------------------------------
// kNN: one block per cluster, 256 threads. d = (qq+pp) - 2*dot (dot FMA-
// ascending like BLAS), LDS distance array per 8192-chunk, 16 argmin rounds
// per chunk (tie -> lower index == stable top_k), exact merge of 2x16.
// Only the neighbor SET matters downstream.
// ---------------------------------------------------------------------------
__global__ __launch_bounds__(256) void knn_kernel(const float* __restrict__ pos,
                                                  const float* __restrict__ pp,
                                                  const int* __restrict__ clusters,
                                                  int* __restrict__ nbr) {
#pragma clang fp contract(off)
    __shared__ float s_d[8192];
    __shared__ float s_rv[4];
    __shared__ int   s_ri[4];
    __shared__ float s_tv[32];
    __shared__ int   s_ti[32];
    const int m = blockIdx.x, t = threadIdx.x;
    const int lane = t & 63, w = t >> 6;

    const int qi = clusters[m];
    const float qx = pos[qi * 3 + 0], qy = pos[qi * 3 + 1], qz = pos[qi * 3 + 2];
    const float qq = ((qx * qx) + (qy * qy)) + (qz * qz);

    for (int chunk = 0; chunk < 2; ++chunk) {
        const int base = chunk << 13;
        __syncthreads();  // protect s_d overwrite vs previous chunk's reads
        for (int i = t; i < 8192; i += 256) {
            const int p = base + i;
            float dot = fmaf(qx, pos[p * 3 + 0], 0.0f);
            dot = fmaf(qy, pos[p * 3 + 1], dot);
            dot = fmaf(qz, pos[p * 3 + 2], dot);
            s_d[i] = (qq + pp[p]) - 2.0f * dot;
        }
        __syncthreads();
        for (int r = 0; r < KNN_K; ++r) {
            float bv = __builtin_inff();
            int   bi = 0x7fffffff;
            for (int i = t; i < 8192; i += 256) {   // i ascending per thread
                float v = s_d[i];
                if (v < bv) { bv = v; bi = i; }     // strict < keeps first
            }
#pragma unroll
            for (int off = 32; off >= 1; off >>= 1) {
                float ov = __shfl_down(bv, off);
                int   oi = __shfl_down(bi, off);
                if (ov < bv || (ov == bv && oi < bi)) { bv = ov; bi = oi; }
            }
            if (lane == 0) { s_rv[w] = bv; s_ri[w] = bi; }
            __syncthreads();
            if (t == 0) {
                float fv = s_rv[0]; int fi = s_ri[0];
#pragma unroll
                for (int ww = 1; ww < 4; ++ww) {
                    if (s_rv[ww] < fv || (s_rv[ww] == fv && s_ri[ww] < fi)) {
                        fv = s_rv[ww]; fi = s_ri[ww];
                    }
                }
                s_tv[chunk * 16 + r] = fv;
                s_ti[chunk * 16 + r] = base + fi;
                s_d[fi] = __builtin_inff();
            }
            __syncthreads();
        }
    }
    if (t == 0) {   // exact merge of two sorted-by-(v,idx) lists
        int a = 0, b = 0;
        for (int r = 0; r < KNN_K; ++r) {
            bool takeA;
            if (b >= 16) takeA = true;
            else if (a >= 16) takeA = false;
            else {
                float va = s_tv[a], vb = s_tv[16 + b];
                takeA = (va < vb) || (va == vb && s_ti[a] < s_ti[16 + b]);
            }
            nbr[m * KNN_K + r] = takeA ? s_ti[a] : s_ti[16 + b];
            if (takeA) ++a; else ++b;
        }
    }
}

// ---------------------------------------------------------------------------
// MLP: grouped[r] = [pos[n]-pos[r>>4] (quirky full-pos indexing!), x[n]],
// h = grouped @ W^T.  PASS 1: accumulate column sum/sumsq.  PASS 2:
// recompute, y = scale*h+shift, out[m,c] = relu(max_k y) (relu∘max=max∘relu),
// plus sub_pos / sub_batch.  64 rows (= 4 whole clusters) x 128 cols / block.
// ---------------------------------------------------------------------------
template <int PASS>
__global__ __launch_bounds__(256) void mlp_kernel(const float* __restrict__ x,
                                                  const float* __restrict__ pos,
                                                  const int* __restrict__ nbr,
                                                  const float* __restrict__ W,
                                                  float* __restrict__ colsum,
                                                  float* __restrict__ colsumsq,
                                                  const float* __restrict__ ss,
                                                  const int* __restrict__ clusters,
                                                  const int* __restrict__ batch,
                                                  float* __restrict__ out) {
    __shared__ __align__(16) float At[FAN_IN][68];     // [i][r], pad 68
    __shared__ __align__(16) float Wl[FAN_IN * 132];   // [i][c], pad 132
    __shared__ float red0[128], red1[128];
    __shared__ float hm[8][132];                       // pass2 half-cluster maxima
    const int tid = threadIdx.x;
    const int R0 = blockIdx.x * 64;

    // stage W transposed
    for (int idx = tid; idx < FAN_IN * 128; idx += 256) {
        int i = idx >> 7, c = idx & 127;
        Wl[i * 132 + c] = W[c * FAN_IN + i];
    }
    // stage A transposed (gather)
    {
        const int wv = tid >> 6, lane = tid & 63;
        for (int r = wv; r < 64; r += 4) {
            const int R = R0 + r;
            const int n = nbr[R];
            At[3 + lane][r] = x[n * C_IN + lane];
            if (lane < 3) {
                const int q = R >> 4;  // faithful to source: cluster ORDINAL indexes pos
                At[lane][r] = pos[n * 3 + lane] - pos[q * 3 + lane];
            }
        }
    }
    if (PASS == 1 && tid < 128) { red0[tid] = 0.0f; red1[tid] = 0.0f; }
    __syncthreads();

    const int g = tid & 31, rg = tid >> 5;
    const int c0 = g * 4, r0 = rg * 8;
    float acc[8][4];
#pragma unroll
    for (int a = 0; a < 8; ++a)
#pragma unroll
        for (int b = 0; b < 4; ++b) acc[a][b] = 0.0f;

    for (int i = 0; i < FAN_IN; ++i) {
        const float4 w4 = *(const float4*)&Wl[i * 132 + c0];
        const float4 a0 = *(const float4*)&At[i][r0];
        const float4 a1 = *(const float4*)&At[i][r0 + 4];
        const float av[8] = {a0.x, a0.y, a0.z, a0.w, a1.x, a1.y, a1.z, a1.w};
        const float wv4[4] = {w4.x, w4.y, w4.z, w4.w};
#pragma unroll
        for (int a = 0; a < 8; ++a)
#pragma unroll
            for (int b = 0; b < 4; ++b) acc[a][b] = fmaf(av[a], wv4[b], acc[a][b]);
    }

    if (PASS == 1) {
#pragma unroll
        for (int b = 0; b < 4; ++b) {
            float s = 0.0f, sq = 0.0f;
#pragma unroll
            for (int a = 0; a < 8; ++a) {
                s += acc[a][b];
                sq = fmaf(acc[a][b], acc[a][b], sq);
            }
            atomicAdd(&red0[c0 + b], s);
            atomicAdd(&red1[c0 + b], sq);
        }
        __syncthreads();
        if (tid < 128) {
            atomicAdd(&colsum[tid], red0[tid]);
            atomicAdd(&colsumsq[tid], red1[tid]);
        }
    } else {
        // rows r0..r0+7 lie in ONE cluster (half of it): reduce then combine
#pragma unroll
        for (int b = 0; b < 4; ++b) {
            const float sc = ss[c0 + b], sh = ss[128 + c0 + b];
            float mx = -__builtin_inff();
#pragma unroll
            for (int a = 0; a < 8; ++a) mx = fmaxf(mx, fmaf(sc, acc[a][b], sh));
            hm[rg][c0 + b] = mx;
        }
        __syncthreads();
        for (int o = tid; o < 512; o += 256) {
            const int cl = o >> 7, c = o & 127;
            const float v = fmaxf(hm[2 * cl][c], hm[2 * cl + 1][c]);
            const int M = blockIdx.x * 4 + cl;
            out[M * 128 + c] = fmaxf(v, 0.0f);
        }
        if (tid < 12) {
            const int cl = tid / 3, l = tid % 3;
            const int M = blockIdx.x * 4 + cl;
            out[524288 + M * 3 + l] = pos[clusters[M] * 3 + l];
        } else if (tid < 16) {
            const int M = blockIdx.x * 4 + (tid - 12);
            out[536576 + M] = (float)batch[clusters[M]];
        }
    }
}

// ---------------------------------------------------------------------------
// stats: scale/shift from column sums (biased var, like torch BN training)
// ---------------------------------------------------------------------------
__global__ void stats_kernel(const float* __restrict__ colsum,
                             const float* __restrict__ colsumsq,
                             const float* __restrict__ gamma,
                             const float* __restrict__ beta,
                             float* __restrict__ ss) {
    const int c = threadIdx.x;
    const float inv_n = 1.0f / (float)N_ROWS;
    const float mean = colsum[c] * inv_n;
    float var = colsumsq[c] * inv_n - mean * mean;
    var = fmaxf(var, 0.0f);
    const float inv = rsqrtf(var + 1e-5f);
    const float sc = gamma[c] * inv;
    ss[c] = sc;
    ss[128 + c] = beta[c] - mean * sc;
}

// ---------------------------------------------------------------------------
extern "C" void kernel_launch(void* const* d_in, const int* in_sizes, int n_in,
                              void* d_out, int out_size, void* d_ws, size_t ws_size,
                              hipStream_t stream) {
    const float* x     = (const float*)d_in[0];
    const float* pos   = (const float*)d_in[1];
    const int*   batch = (const int*)d_in[2];
    const float* W     = (const float*)d_in[3];
    const float* gamma = (const float*)d_in[4];
    const float* beta  = (const float*)d_in[5];
    float* out = (float*)d_out;
    float* wsf = (float*)d_ws;

    int*   clusters = (int*)d_ws;            // [4096]
    int*   nbr      = clusters + 4096;       // [65536]
    float* pp       = wsf + 69632;           // [16384]
    float* colsum   = wsf + 86016;           // [128]
    float* colsumsq = wsf + 86144;           // [128]
    float* ss       = wsf + 86272;           // [256]

    init_kernel<<<dim3(64), dim3(256), 0, stream>>>(pos, pp, colsum);
    fps_kernel<<<dim3(1), dim3(512), 0, stream>>>(pos, clusters);
    knn_kernel<<<dim3(N_CLUSTERS), dim3(256), 0, stream>>>(pos, pp, clusters, nbr);
    mlp_kernel<1><<<dim3(1024), dim3(256), 0, stream>>>(x, pos, nbr, W, colsum, colsumsq,
                                                        ss, clusters, batch, out);
    stats_kernel<<<dim3(1), dim3(128), 0, stream>>>(colsum, colsumsq, gamma, beta, ss);
    mlp_kernel<2><<<dim3(1024), dim3(256), 0, stream>>>(x, pos, nbr, W, colsum, colsumsq,
                                                        ss, clusters, batch, out);
}

// Round 12
// 5040.226 us; speedup vs baseline: 1.4490x; 1.0093x over previous
//
#include <hip/hip_runtime.h>
#include <math.h>

#define N_PTS 16384
#define N_CLUSTERS 4096
#define KNN_K 16
#define C_IN 64
#define C_OUT 128
#define FAN_IN 67
#define N_ROWS (N_CLUSTERS * KNN_K)   // 65536
#define NBINS 256

typedef float vf2 __attribute__((ext_vector_type(2)));
typedef unsigned long long u64;
typedef u64 u64x2 __attribute__((ext_vector_type(2)));

// ---------------------------------------------------------------------------
// init: pp[i] = |pos_i|^2 (reference op order, no FMA), zero colsum/colsumsq
// ---------------------------------------------------------------------------
__global__ void init_kernel(const float* __restrict__ pos, float* __restrict__ pp,
                            float* __restrict__ cz) {
#pragma clang fp contract(off)
    int i = blockIdx.x * 256 + threadIdx.x;
    if (i < N_PTS) {
        float a = pos[i * 3 + 0], b = pos[i * 3 + 1], c = pos[i * 3 + 2];
        pp[i] = ((a * a) + (b * b)) + (c * c);
    }
    if (blockIdx.x == 0 && threadIdx.x < 256) cz[threadIdx.x] = 0.0f;
}

// ---------------------------------------------------------------------------
// FPS v15 = v10 RESTORED VERBATIM (best verified: fps 4499us, total 5031us).
// Session history of the fps serial-chain floor (~2670 cyc/step x 4095):
//   v4  6908us  value-only reduce + rare-path index recovery
//   v6  5994us  512 thr / 8 waves (tail not wave-count-scaled)
//   v7  6576us  REGRESS: packed-asm operand marshaling
//   v8  7340us  REGRESS: multi-CU mailbox (cross-XCD sync >= 1500cyc/step)
//   v9  6340us  x-slab pruning (VALU -62%) but 2-barrier tail dominated
//   v10 4499us  + single-barrier parity keyed reduce  <-- THIS
//   v11 5472us  REGRESS: octants (corner-at-mean activates more waves)
//   v12 6781us  REGRESS: intra-wave chunk s_cbranch overhead
//   v13 4556us  own-key-in-register: neutral
//   v14 crash   AGPR clobber fence exceeds register budget; theory retracted
//     (scalarized-update instruction count ~456 instrs fully explains the
//      measured VALU budget; no accvgpr traffic needed to close the model)
// Structure:
//   - x-slab partition: 256-bin histogram + ticketed placement (one-time);
//     wave w owns slots [2048w,+2048) = contiguous x-slab, exact [lo,hi].
//   - exact skip: dist(cx,[lo,hi])^2 >= wm => whole-wave update is identity
//     (monotone RN rounding: d_p >= fl(dx_p^2) >= fl(dm^2) >= wm >= md_p);
//     skipped wave's cached key stays exact.
//   - key = (f32bits(max md)<<32) | ~min_orig_idx; u64 max == (max value,
//     tie -> min ORIGINAL index) == jnp.argmax first-occurrence.
//   - single-barrier reduce: every wave publishes its (cached or fresh) key
//     to parity buffer s_wkey[(step+1)&1][w]; ONE barrier; all threads read
//     8 keys (4x b128 broadcast) + 7-compare u64 max tree -> winner.
//   - winner coords: uniform readfirstlane + scalar load (off VALU/LDS).
//   - cluster ids accumulate in LDS, bulk coalesced store at the end.
// Update math: d=((dx*dx)+(dy*dy))+(dz*dz), no FMA (contract off),
// fmin/fmax/select only -> bit-exact winner sequence vs reference.
// ---------------------------------------------------------------------------
__global__ __launch_bounds__(512)
__attribute__((amdgpu_waves_per_eu(2, 2)))
void fps_kernel(const float* __restrict__ pos, int* __restrict__ clusters) {
#pragma clang fp contract(off)
    __shared__ unsigned short s_perm[N_PTS];     // 32KB: slot -> original index
    __shared__ int s_cluster[N_CLUSTERS];        // 16KB result accumulator
    __shared__ int s_hist[NBINS];                // histogram -> ticket base
    __shared__ float s_red[16];                  // setup reduce scratch
    __shared__ __align__(16) u64 s_wkey[2][8];   // parity-buffered wave keys
    const int t = threadIdx.x;
    const int w = t >> 6, lane = t & 63;
    const int wbase = w << 11;                   // wave owns slots [w*2048,+2048)

    // ---- setup pass 0: global x min/max ----
    float txmin = __builtin_inff(), txmax = -__builtin_inff();
#pragma unroll
    for (int k = 0; k < 32; ++k) {
        const float xv = pos[(t + (k << 9)) * 3];
        txmin = fminf(txmin, xv);
        txmax = fmaxf(txmax, xv);
    }
#pragma unroll
    for (int off = 32; off >= 1; off >>= 1) {
        txmin = fminf(txmin, __shfl_xor(txmin, off));
        txmax = fmaxf(txmax, __shfl_xor(txmax, off));
    }
    if (lane == 0) { s_red[w] = txmin; s_red[8 + w] = txmax; }
    if (t < NBINS) s_hist[t] = 0;
    if (t == 0) s_cluster[0] = 0;
    __syncthreads();
    float gxmin = s_red[0], gxmax = s_red[8];
#pragma unroll
    for (int i = 1; i < 8; ++i) {
        gxmin = fminf(gxmin, s_red[i]);
        gxmax = fmaxf(gxmax, s_red[8 + i]);
    }
    const float binv = (float)NBINS / (gxmax - gxmin);

    // ---- setup pass 1: histogram ----
#pragma unroll
    for (int k = 0; k < 32; ++k) {
        const int i = t + (k << 9);
        int b = (int)((pos[i * 3] - gxmin) * binv);
        b = (b < 0) ? 0 : ((b > NBINS - 1) ? NBINS - 1 : b);
        atomicAdd(&s_hist[b], 1);
    }
    __syncthreads();
    if (t == 0) {   // serial prefix sum (one-time)
        int run = 0;
        for (int b = 0; b < NBINS; ++b) {
            const int c = s_hist[b];
            s_hist[b] = run;
            run += c;
        }
    }
    __syncthreads();
    // ---- setup pass 2: placement (bijective by tickets) ----
#pragma unroll
    for (int k = 0; k < 32; ++k) {
        const int i = t + (k << 9);
        int b = (int)((pos[i * 3] - gxmin) * binv);
        b = (b < 0) ? 0 : ((b > NBINS - 1) ? NBINS - 1 : b);
        const int dest = atomicAdd(&s_hist[b], 1);
        s_perm[dest] = (unsigned short)i;
    }
    __syncthreads();

    // ---- gather coords + packed original indices + exact wave x-interval ----
    vf2 ax[16], ay[16], az[16], mdv[16];
    unsigned int oid[16];
    float mnx = __builtin_inff(), mxx = -__builtin_inff();
#pragma unroll
    for (int a = 0; a < 16; ++a) {
        const int s0 = wbase + (((a << 1) | 0) << 6) + lane;
        const int s1 = wbase + (((a << 1) | 1) << 6) + lane;
        const unsigned int o0 = s_perm[s0], o1 = s_perm[s1];
        oid[a] = (o1 << 16) | o0;
        ax[a] = (vf2){pos[o0 * 3 + 0], pos[o1 * 3 + 0]};
        ay[a] = (vf2){pos[o0 * 3 + 1], pos[o1 * 3 + 1]};
        az[a] = (vf2){pos[o0 * 3 + 2], pos[o1 * 3 + 2]};
        mdv[a] = (vf2){__builtin_inff(), __builtin_inff()};
        mnx = fminf(mnx, fminf(ax[a].x, ax[a].y));
        mxx = fmaxf(mxx, fmaxf(ax[a].x, ax[a].y));
    }
#pragma unroll
    for (int off = 32; off >= 1; off >>= 1) {
        mnx = fminf(mnx, __shfl_xor(mnx, off));
        mxx = fmaxf(mxx, __shfl_xor(mxx, off));
    }
    if (lane == 0) { s_red[w] = mnx; s_red[8 + w] = mxx; }
    __syncthreads();
    const float lo = s_red[w], hi = s_red[8 + w];

    float lx = pos[0], ly = pos[1], lz = pos[2];
    u64 wkey = 0;   // lane63 holds the wave's cached key after each active step

// DPP pair-max on (hi_,lo_) u64 key; old=0 masked lanes never win (lo_!=0).
#define PAIR_STAGE(CTRL, RM)                                                          \
    do {                                                                              \
        unsigned int ohi = (unsigned int)__builtin_amdgcn_update_dpp(                 \
            0, (int)hi_, (CTRL), (RM), 0xF, false);                                   \
        unsigned int olo = (unsigned int)__builtin_amdgcn_update_dpp(                 \
            0, (int)lo_, (CTRL), (RM), 0xF, false);                                   \
        u64 cur = ((u64)hi_ << 32) | lo_;                                             \
        u64 oth = ((u64)ohi << 32) | olo;                                             \
        if (oth > cur) { hi_ = ohi; lo_ = olo; }                                      \
    } while (0)

// active-wave body: packed update + min-orig-idx recovery + DPP -> wkey
#define UPDATE_AND_KEY()                                                              \
    do {                                                                              \
        const vf2 lxv = (vf2){lx, lx}, lyv = (vf2){ly, ly}, lzv = (vf2){lz, lz};      \
        vf2 bm = (vf2){0.0f, 0.0f};                                                   \
        _Pragma("unroll")                                                             \
        for (int a = 0; a < 16; ++a) {                                                \
            vf2 dx = ax[a] - lxv;                                                     \
            vf2 dy = ay[a] - lyv;                                                     \
            vf2 dz = az[a] - lzv;                                                     \
            vf2 d = ((dx * dx) + (dy * dy)) + (dz * dz);                              \
            vf2 m;                                                                    \
            m.x = fminf(mdv[a].x, d.x);                                               \
            m.y = fminf(mdv[a].y, d.y);                                               \
            mdv[a] = m;                                                               \
            bm = __builtin_elementwise_max(bm, m);                                    \
        }                                                                             \
        const float bv = fmaxf(bm.x, bm.y);                                           \
        unsigned int mi = 0xffffffffu;                                                \
        _Pragma("unroll")                                                             \
        for (int a = 0; a < 16; ++a) {                                                \
            const unsigned int c0 =                                                   \
                (mdv[a].x == bv) ? (oid[a] & 0xffffu) : 0xffffffffu;                  \
            const unsigned int c1 =                                                   \
                (mdv[a].y == bv) ? (oid[a] >> 16) : 0xffffffffu;                      \
            const unsigned int cc = (c0 < c1) ? c0 : c1;                              \
            mi = (cc < mi) ? cc : mi;                                                 \
        }                                                                             \
        unsigned int hi_ = __float_as_uint(bv);                                       \
        unsigned int lo_ = ~mi;                                                       \
        PAIR_STAGE(0x111, 0xF);                                                       \
        PAIR_STAGE(0x112, 0xF);                                                       \
        PAIR_STAGE(0x114, 0xF);                                                       \
        PAIR_STAGE(0x118, 0xF);                                                       \
        PAIR_STAGE(0x142, 0xA);                                                       \
        PAIR_STAGE(0x143, 0xC);                                                       \
        wkey = ((u64)hi_ << 32) | lo_;                                                \
    } while (0)

    // ---- prologue: step-0 update vs cluster 0, publish keys to buf[1] ----
    UPDATE_AND_KEY();
    if (lane == 63) s_wkey[1][w] = wkey;
    __syncthreads();

    for (int step = 1; step < N_CLUSTERS; ++step) {
        const int p = step & 1;
        // ---- read 8 wave keys (broadcast) + u64 max tree ----
        const u64x2* kp = (const u64x2*)&s_wkey[p][0];
        const u64x2 k0 = kp[0], k1 = kp[1], k2 = kp[2], k3 = kp[3];
        u64 b0 = (k0.x > k0.y) ? k0.x : k0.y;
        u64 b1 = (k1.x > k1.y) ? k1.x : k1.y;
        u64 b2 = (k2.x > k2.y) ? k2.x : k2.y;
        u64 b3 = (k3.x > k3.y) ? k3.x : k3.y;
        b0 = (b1 > b0) ? b1 : b0;
        b2 = (b3 > b2) ? b3 : b2;
        const u64 bkey = (b2 > b0) ? b2 : b0;
        const unsigned int win = ~((unsigned int)bkey);
        if (t == 0) s_cluster[step] = (int)win;

        // ---- uniform scalar fetch of winner coords ----
        const unsigned int winu =
            (unsigned int)__builtin_amdgcn_readfirstlane((int)win);
        lx = pos[winu * 3 + 0];
        ly = pos[winu * 3 + 1];
        lz = pos[winu * 3 + 2];

        // ---- exact skip test (wave-uniform; wm = own cached key's value) ----
        const u64 own = s_wkey[p][w];
        const float wm = __uint_as_float((unsigned int)(own >> 32));
        const float dm = fmaxf(fmaxf(lo - lx, lx - hi), 0.0f);
        const bool act = (dm * dm < wm);
        if (__builtin_amdgcn_readfirstlane((int)act)) UPDATE_AND_KEY();

        // ---- publish (cached or fresh) key for the NEXT step; one barrier ----
        if (lane == 63) s_wkey[p ^ 1][w] = wkey;
        __syncthreads();
    }
#undef UPDATE_AND_KEY
#undef PAIR_STAGE

    // bulk coalesced store of the cluster list
    for (int i = t; i < N_CLUSTERS; i += 512) clusters[i] = s_cluster[i];
}

// ---------------------------------------------------------------------------
// kNN: one block per cluster, 256 threads. d = (qq+pp) - 2*dot (dot FMA-
// ascending like BLAS), LDS distance array per 8192-chunk, 16 argmin rounds
// per chunk (tie -> lower index == stable top_k), exact merge of 2x16.
// Only the neighbor SET matters downstream.
// ---------------------------------------------------------------------------
__global__ __launch_bounds__(256) void knn_kernel(const float* __restrict__ pos,
                                                  const float* __restrict__ pp,
                                                  const int* __restrict__ clusters,
                                                  int* __restrict__ nbr) {
#pragma clang fp contract(off)
    __shared__ float s_d[8192];
    __shared__ float s_rv[4];
    __shared__ int   s_ri[4];
    __shared__ float s_tv[32];
    __shared__ int   s_ti[32];
    const int m = blockIdx.x, t = threadIdx.x;
    const int lane = t & 63, w = t >> 6;

    const int qi = clusters[m];
    const float qx = pos[qi * 3 + 0], qy = pos[qi * 3 + 1], qz = pos[qi * 3 + 2];
    const float qq = ((qx * qx) + (qy * qy)) + (qz * qz);

    for (int chunk = 0; chunk < 2; ++chunk) {
        const int base = chunk << 13;
        __syncthreads();  // protect s_d overwrite vs previous chunk's reads
        for (int i = t; i < 8192; i += 256) {
            const int p = base + i;
            float dot = fmaf(qx, pos[p * 3 + 0], 0.0f);
            dot = fmaf(qy, pos[p * 3 + 1], dot);
            dot = fmaf(qz, pos[p * 3 + 2], dot);
            s_d[i] = (qq + pp[p]) - 2.0f * dot;
        }
        __syncthreads();
        for (int r = 0; r < KNN_K; ++r) {
            float bv = __builtin_inff();
            int   bi = 0x7fffffff;
            for (int i = t; i < 8192; i += 256) {   // i ascending per thread
                float v = s_d[i];
                if (v < bv) { bv = v; bi = i; }     // strict < keeps first
            }
#pragma unroll
            for (int off = 32; off >= 1; off >>= 1) {
                float ov = __shfl_down(bv, off);
                int   oi = __shfl_down(bi, off);
                if (ov < bv || (ov == bv && oi < bi)) { bv = ov; bi = oi; }
            }
            if (lane == 0) { s_rv[w] = bv; s_ri[w] = bi; }
            __syncthreads();
            if (t == 0) {
                float fv = s_rv[0]; int fi = s_ri[0];
#pragma unroll
                for (int ww = 1; ww < 4; ++ww) {
                    if (s_rv[ww] < fv || (s_rv[ww] == fv && s_ri[ww] < fi)) {
                        fv = s_rv[ww]; fi = s_ri[ww];
                    }
                }
                s_tv[chunk * 16 + r] = fv;
                s_ti[chunk * 16 + r] = base + fi;
                s_d[fi] = __builtin_inff();
            }
            __syncthreads();
        }
    }
    if (t == 0) {   // exact merge of two sorted-by-(v,idx) lists
        int a = 0, b = 0;
        for (int r = 0; r < KNN_K; ++r) {
            bool takeA;
            if (b >= 16) takeA = true;
            else if (a >= 16) takeA = false;
            else {
                float va = s_tv[a], vb = s_tv[16 + b];
                takeA = (va < vb) || (va == vb && s_ti[a] < s_ti[16 + b]);
            }
            nbr[m * KNN_K + r] = takeA ? s_ti[a] : s_ti[16 + b];
            if (takeA) ++a; else ++b;
        }
    }
}

// ---------------------------------------------------------------------------
// MLP: grouped[r] = [pos[n]-pos[r>>4] (quirky full-pos indexing!), x[n]],
// h = grouped @ W^T.  PASS 1: accumulate column sum/sumsq.  PASS 2:
// recompute, y = scale*h+shift, out[m,c] = relu(max_k y) (relu∘max=max∘relu),
// plus sub_pos / sub_batch.  64 rows (= 4 whole clusters) x 128 cols / block.
// ---------------------------------------------------------------------------
template <int PASS>
__global__ __launch_bounds__(256) void mlp_kernel(const float* __restrict__ x,
                                                  const float* __restrict__ pos,
                                                  const int* __restrict__ nbr,
                                                  const float* __restrict__ W,
                                                  float* __restrict__ colsum,
                                                  float* __restrict__ colsumsq,
                                                  const float* __restrict__ ss,
                                                  const int* __restrict__ clusters,
                                                  const int* __restrict__ batch,
                                                  float* __restrict__ out) {
    __shared__ __align__(16) float At[FAN_IN][68];     // [i][r], pad 68
    __shared__ __align__(16) float Wl[FAN_IN * 132];   // [i][c], pad 132
    __shared__ float red0[128], red1[128];
    __shared__ float hm[8][132];                       // pass2 half-cluster maxima
    const int tid = threadIdx.x;
    const int R0 = blockIdx.x * 64;

    // stage W transposed
    for (int idx = tid; idx < FAN_IN * 128; idx += 256) {
        int i = idx >> 7, c = idx & 127;
        Wl[i * 132 + c] = W[c * FAN_IN + i];
    }
    // stage A transposed (gather)
    {
        const int wv = tid >> 6, lane = tid & 63;
        for (int r = wv; r < 64; r += 4) {
            const int R = R0 + r;
            const int n = nbr[R];
            At[3 + lane][r] = x[n * C_IN + lane];
            if (lane < 3) {
                const int q = R >> 4;  // faithful to source: cluster ORDINAL indexes pos
                At[lane][r] = pos[n * 3 + lane] - pos[q * 3 + lane];
            }
        }
    }
    if (PASS == 1 && tid < 128) { red0[tid] = 0.0f; red1[tid] = 0.0f; }
    __syncthreads();

    const int g = tid & 31, rg = tid >> 5;
    const int c0 = g * 4, r0 = rg * 8;
    float acc[8][4];
#pragma unroll
    for (int a = 0; a < 8; ++a)
#pragma unroll
        for (int b = 0; b < 4; ++b) acc[a][b] = 0.0f;

    for (int i = 0; i < FAN_IN; ++i) {
        const float4 w4 = *(const float4*)&Wl[i * 132 + c0];
        const float4 a0 = *(const float4*)&At[i][r0];
        const float4 a1 = *(const float4*)&At[i][r0 + 4];
        const float av[8] = {a0.x, a0.y, a0.z, a0.w, a1.x, a1.y, a1.z, a1.w};
        const float wv4[4] = {w4.x, w4.y, w4.z, w4.w};
#pragma unroll
        for (int a = 0; a < 8; ++a)
#pragma unroll
            for (int b = 0; b < 4; ++b) acc[a][b] = fmaf(av[a], wv4[b], acc[a][b]);
    }

    if (PASS == 1) {
#pragma unroll
        for (int b = 0; b < 4; ++b) {
            float s = 0.0f, sq = 0.0f;
#pragma unroll
            for (int a = 0; a < 8; ++a) {
                s += acc[a][b];
                sq = fmaf(acc[a][b], acc[a][b], sq);
            }
            atomicAdd(&red0[c0 + b], s);
            atomicAdd(&red1[c0 + b], sq);
        }
        __syncthreads();
        if (tid < 128) {
            atomicAdd(&colsum[tid], red0[tid]);
            atomicAdd(&colsumsq[tid], red1[tid]);
        }
    } else {
        // rows r0..r0+7 lie in ONE cluster (half of it): reduce then combine
#pragma unroll
        for (int b = 0; b < 4; ++b) {
            const float sc = ss[c0 + b], sh = ss[128 + c0 + b];
            float mx = -__builtin_inff();
#pragma unroll
            for (int a = 0; a < 8; ++a) mx = fmaxf(mx, fmaf(sc, acc[a][b], sh));
            hm[rg][c0 + b] = mx;
        }
        __syncthreads();
        for (int o = tid; o < 512; o += 256) {
            const int cl = o >> 7, c = o & 127;
            const float v = fmaxf(hm[2 * cl][c], hm[2 * cl + 1][c]);
            const int M = blockIdx.x * 4 + cl;
            out[M * 128 + c] = fmaxf(v, 0.0f);
        }
        if (tid < 12) {
            const int cl = tid / 3, l = tid % 3;
            const int M = blockIdx.x * 4 + cl;
            out[524288 + M * 3 + l] = pos[clusters[M] * 3 + l];
        } else if (tid < 16) {
            const int M = blockIdx.x * 4 + (tid - 12);
            out[536576 + M] = (float)batch[clusters[M]];
        }
    }
}

// ---------------------------------------------------------------------------
// stats: scale/shift from column sums (biased var, like torch BN training)
// ---------------------------------------------------------------------------
__global__ void stats_kernel(const float* __restrict__ colsum,
                             const float* __restrict__ colsumsq,
                             const float* __restrict__ gamma,
                             const float* __restrict__ beta,
                             float* __restrict__ ss) {
    const int c = threadIdx.x;
    const float inv_n = 1.0f / (float)N_ROWS;
    const float mean = colsum[c] * inv_n;
    float var = colsumsq[c] * inv_n - mean * mean;
    var = fmaxf(var, 0.0f);
    const float inv = rsqrtf(var + 1e-5f);
    const float sc = gamma[c] * inv;
    ss[c] = sc;
    ss[128 + c] = beta[c] - mean * sc;
}

// ---------------------------------------------------------------------------
extern "C" void kernel_launch(void* const* d_in, const int* in_sizes, int n_in,
                              void* d_out, int out_size, void* d_ws, size_t ws_size,
                              hipStream_t stream) {
    const float* x     = (const float*)d_in[0];
    const float* pos   = (const float*)d_in[1];
    const int*   batch = (const int*)d_in[2];
    const float* W     = (const float*)d_in[3];
    const float* gamma = (const float*)d_in[4];
    const float* beta  = (const float*)d_in[5];
    float* out = (float*)d_out;
    float* wsf = (float*)d_ws;

    int*   clusters = (int*)d_ws;            // [4096]
    int*   nbr      = clusters + 4096;       // [65536]
    float* pp       = wsf + 69632;           // [16384]
    float* colsum   = wsf + 86016;           // [128]
    float* colsumsq = wsf + 86144;           // [128]
    float* ss       = wsf + 86272;           // [256]

    init_kernel<<<dim3(64), dim3(256), 0, stream>>>(pos, pp, colsum);
    fps_kernel<<<dim3(1), dim3(512), 0, stream>>>(pos, clusters);
    knn_kernel<<<dim3(N_CLUSTERS), dim3(256), 0, stream>>>(pos, pp, clusters, nbr);
    mlp_kernel<1><<<dim3(1024), dim3(256), 0, stream>>>(x, pos, nbr, W, colsum, colsumsq,
                                                        ss, clusters, batch, out);
    stats_kernel<<<dim3(1), dim3(128), 0, stream>>>(colsum, colsumsq, gamma, beta, ss);
    mlp_kernel<2><<<dim3(1024), dim3(256), 0, stream>>>(x, pos, nbr, W, colsum, colsumsq,
                                                        ss, clusters, batch, out);
}

// Round 13
// 4644.012 us; speedup vs baseline: 1.5727x; 1.0853x over previous
//
#include <hip/hip_runtime.h>
#include <math.h>

#define N_PTS 16384
#define N_CLUSTERS 4096
#define KNN_K 16
#define C_IN 64
#define C_OUT 128
#define FAN_IN 67
#define N_ROWS (N_CLUSTERS * KNN_K)   // 65536
#define NBINS 256

typedef float vf2 __attribute__((ext_vector_type(2)));
typedef unsigned long long u64;
typedef u64 u64x2 __attribute__((ext_vector_type(2)));

// ---------------------------------------------------------------------------
// init: pp[i] = |pos_i|^2 (reference op order, no FMA), zero colsum/colsumsq
// ---------------------------------------------------------------------------
__global__ void init_kernel(const float* __restrict__ pos, float* __restrict__ pp,
                            float* __restrict__ cz) {
#pragma clang fp contract(off)
    int i = blockIdx.x * 256 + threadIdx.x;
    if (i < N_PTS) {
        float a = pos[i * 3 + 0], b = pos[i * 3 + 1], c = pos[i * 3 + 2];
        pp[i] = ((a * a) + (b * b)) + (c * c);
    }
    if (blockIdx.x == 0 && threadIdx.x < 256) cz[threadIdx.x] = 0.0f;
}

// ---------------------------------------------------------------------------
// FPS v16 = v10 structure with 16 WAVES x HALF-SLABS (1024 threads, 16
// pts/thread, 8 vf2 pairs -> ~80 VGPR, 4 waves/SIMD).
// Rationale (v15 budget audit): step = active-wave update ISSUE (912 cyc at
// 32 pts/thread) + ~1700 cyc wave-count-invariant tail (v4->v6 proved the
// tail doesn't scale with wave count).  Contiguous active waves land on
// distinct SIMDs (w%4) until the active run reaches 5, so halving the
// per-wave slab halves the critical-path update to ~460 cyc while the two
// half-slab waves run in parallel on different SIMDs.  Key table 8 -> 16
// entries (+4 b128 reads, 15-compare tree, ~+60 cyc) -- net win predicted.
// All v10-proven machinery retained verbatim, just w in [0,16):
//   - x-slab partition (256-bin histogram + ticketed placement, one-time);
//     wave w owns slots [1024w,+1024) with exact interval [lo,hi].
//   - exact skip: dist(cx,[lo,hi])^2 >= wm => whole-wave update is identity
//     (monotone RN: d_p >= fl(dx_p^2) >= fl(dm^2) >= wm >= md_p); skipped
//     wave's cached key stays exact.
//   - key = (f32bits(max md)<<32) | ~min_orig_idx; u64 max == (max value,
//     tie -> min ORIGINAL index) == jnp.argmax first-occurrence;
//     placement-invariant.
//   - single-barrier parity keyed reduce; winner coords via readfirstlane +
//     scalar load; cluster ids in LDS, bulk store at end.
// Update math: d=((dx*dx)+(dy*dy))+(dz*dz), no FMA (contract off),
// fmin/fmax/select only -> bit-exact winner sequence vs reference.
// ---------------------------------------------------------------------------
__global__ __launch_bounds__(1024)
__attribute__((amdgpu_waves_per_eu(4, 4)))
void fps_kernel(const float* __restrict__ pos, int* __restrict__ clusters) {
#pragma clang fp contract(off)
    __shared__ unsigned short s_perm[N_PTS];     // 32KB: slot -> original index
    __shared__ int s_cluster[N_CLUSTERS];        // 16KB result accumulator
    __shared__ int s_hist[NBINS];                // histogram -> ticket base
    __shared__ float s_red[32];                  // setup reduce scratch (16 waves x2)
    __shared__ __align__(16) u64 s_wkey[2][16];  // parity-buffered wave keys
    const int t = threadIdx.x;
    const int w = t >> 6, lane = t & 63;
    const int wbase = w << 10;                   // wave owns slots [w*1024,+1024)

    // ---- setup pass 0: global x min/max ----
    float txmin = __builtin_inff(), txmax = -__builtin_inff();
#pragma unroll
    for (int k = 0; k < 16; ++k) {
        const float xv = pos[(t + (k << 10)) * 3];
        txmin = fminf(txmin, xv);
        txmax = fmaxf(txmax, xv);
    }
#pragma unroll
    for (int off = 32; off >= 1; off >>= 1) {
        txmin = fminf(txmin, __shfl_xor(txmin, off));
        txmax = fmaxf(txmax, __shfl_xor(txmax, off));
    }
    if (lane == 0) { s_red[w] = txmin; s_red[16 + w] = txmax; }
    if (t < NBINS) s_hist[t] = 0;
    if (t == 0) s_cluster[0] = 0;
    __syncthreads();
    float gxmin = s_red[0], gxmax = s_red[16];
#pragma unroll
    for (int i = 1; i < 16; ++i) {
        gxmin = fminf(gxmin, s_red[i]);
        gxmax = fmaxf(gxmax, s_red[16 + i]);
    }
    const float binv = (float)NBINS / (gxmax - gxmin);

    // ---- setup pass 1: histogram ----
#pragma unroll
    for (int k = 0; k < 16; ++k) {
        const int i = t + (k << 10);
        int b = (int)((pos[i * 3] - gxmin) * binv);
        b = (b < 0) ? 0 : ((b > NBINS - 1) ? NBINS - 1 : b);
        atomicAdd(&s_hist[b], 1);
    }
    __syncthreads();
    if (t == 0) {   // serial prefix sum (one-time)
        int run = 0;
        for (int b = 0; b < NBINS; ++b) {
            const int c = s_hist[b];
            s_hist[b] = run;
            run += c;
        }
    }
    __syncthreads();
    // ---- setup pass 2: placement (bijective by tickets) ----
#pragma unroll
    for (int k = 0; k < 16; ++k) {
        const int i = t + (k << 10);
        int b = (int)((pos[i * 3] - gxmin) * binv);
        b = (b < 0) ? 0 : ((b > NBINS - 1) ? NBINS - 1 : b);
        const int dest = atomicAdd(&s_hist[b], 1);
        s_perm[dest] = (unsigned short)i;
    }
    __syncthreads();

    // ---- gather coords + packed original indices + exact wave x-interval ----
    vf2 ax[8], ay[8], az[8], mdv[8];
    unsigned int oid[8];
    float mnx = __builtin_inff(), mxx = -__builtin_inff();
#pragma unroll
    for (int a = 0; a < 8; ++a) {
        const int s0 = wbase + (((a << 1) | 0) << 6) + lane;
        const int s1 = wbase + (((a << 1) | 1) << 6) + lane;
        const unsigned int o0 = s_perm[s0], o1 = s_perm[s1];
        oid[a] = (o1 << 16) | o0;
        ax[a] = (vf2){pos[o0 * 3 + 0], pos[o1 * 3 + 0]};
        ay[a] = (vf2){pos[o0 * 3 + 1], pos[o1 * 3 + 1]};
        az[a] = (vf2){pos[o0 * 3 + 2], pos[o1 * 3 + 2]};
        mdv[a] = (vf2){__builtin_inff(), __builtin_inff()};
        mnx = fminf(mnx, fminf(ax[a].x, ax[a].y));
        mxx = fmaxf(mxx, fmaxf(ax[a].x, ax[a].y));
    }
#pragma unroll
    for (int off = 32; off >= 1; off >>= 1) {
        mnx = fminf(mnx, __shfl_xor(mnx, off));
        mxx = fmaxf(mxx, __shfl_xor(mxx, off));
    }
    if (lane == 0) { s_red[w] = mnx; s_red[16 + w] = mxx; }
    __syncthreads();
    const float lo = s_red[w], hi = s_red[16 + w];

    float lx = pos[0], ly = pos[1], lz = pos[2];
    u64 wkey = 0;   // lane63 holds the wave's cached key after each active step

// DPP pair-max on (hi_,lo_) u64 key; old=0 masked lanes never win (lo_!=0).
#define PAIR_STAGE(CTRL, RM)                                                          \
    do {                                                                              \
        unsigned int ohi = (unsigned int)__builtin_amdgcn_update_dpp(                 \
            0, (int)hi_, (CTRL), (RM), 0xF, false);                                   \
        unsigned int olo = (unsigned int)__builtin_amdgcn_update_dpp(                 \
            0, (int)lo_, (CTRL), (RM), 0xF, false);                                   \
        u64 cur = ((u64)hi_ << 32) | lo_;                                             \
        u64 oth = ((u64)ohi << 32) | olo;                                             \
        if (oth > cur) { hi_ = ohi; lo_ = olo; }                                      \
    } while (0)

// active-wave body: packed update + min-orig-idx recovery + DPP -> wkey
#define UPDATE_AND_KEY()                                                              \
    do {                                                                              \
        const vf2 lxv = (vf2){lx, lx}, lyv = (vf2){ly, ly}, lzv = (vf2){lz, lz};      \
        vf2 bm = (vf2){0.0f, 0.0f};                                                   \
        _Pragma("unroll")                                                             \
        for (int a = 0; a < 8; ++a) {                                                 \
            vf2 dx = ax[a] - lxv;                                                     \
            vf2 dy = ay[a] - lyv;                                                     \
            vf2 dz = az[a] - lzv;                                                     \
            vf2 d = ((dx * dx) + (dy * dy)) + (dz * dz);                              \
            vf2 m;                                                                    \
            m.x = fminf(mdv[a].x, d.x);                                               \
            m.y = fminf(mdv[a].y, d.y);                                               \
            mdv[a] = m;                                                               \
            bm = __builtin_elementwise_max(bm, m);                                    \
        }                                                                             \
        const float bv = fmaxf(bm.x, bm.y);                                           \
        unsigned int mi = 0xffffffffu;                                                \
        _Pragma("unroll")                                                             \
        for (int a = 0; a < 8; ++a) {                                                 \
            const unsigned int c0 =                                                   \
                (mdv[a].x == bv) ? (oid[a] & 0xffffu) : 0xffffffffu;                  \
            const unsigned int c1 =                                                   \
                (mdv[a].y == bv) ? (oid[a] >> 16) : 0xffffffffu;                      \
            const unsigned int cc = (c0 < c1) ? c0 : c1;                              \
            mi = (cc < mi) ? cc : mi;                                                 \
        }                                                                             \
        unsigned int hi_ = __float_as_uint(bv);                                       \
        unsigned int lo_ = ~mi;                                                       \
        PAIR_STAGE(0x111, 0xF);                                                       \
        PAIR_STAGE(0x112, 0xF);                                                       \
        PAIR_STAGE(0x114, 0xF);                                                       \
        PAIR_STAGE(0x118, 0xF);                                                       \
        PAIR_STAGE(0x142, 0xA);                                                       \
        PAIR_STAGE(0x143, 0xC);                                                       \
        wkey = ((u64)hi_ << 32) | lo_;                                                \
    } while (0)

    // ---- prologue: step-0 update vs cluster 0, publish keys to buf[1] ----
    UPDATE_AND_KEY();
    if (lane == 63) s_wkey[1][w] = wkey;
    __syncthreads();

    for (int step = 1; step < N_CLUSTERS; ++step) {
        const int p = step & 1;
        // ---- read 16 wave keys (broadcast b128) + u64 max tree ----
        const u64x2* kp = (const u64x2*)&s_wkey[p][0];
        const u64x2 k0 = kp[0], k1 = kp[1], k2 = kp[2], k3 = kp[3];
        const u64x2 k4 = kp[4], k5 = kp[5], k6 = kp[6], k7 = kp[7];
        u64 b0 = (k0.x > k0.y) ? k0.x : k0.y;
        u64 b1 = (k1.x > k1.y) ? k1.x : k1.y;
        u64 b2 = (k2.x > k2.y) ? k2.x : k2.y;
        u64 b3 = (k3.x > k3.y) ? k3.x : k3.y;
        u64 b4 = (k4.x > k4.y) ? k4.x : k4.y;
        u64 b5 = (k5.x > k5.y) ? k5.x : k5.y;
        u64 b6 = (k6.x > k6.y) ? k6.x : k6.y;
        u64 b7 = (k7.x > k7.y) ? k7.x : k7.y;
        b0 = (b1 > b0) ? b1 : b0;
        b2 = (b3 > b2) ? b3 : b2;
        b4 = (b5 > b4) ? b5 : b4;
        b6 = (b7 > b6) ? b7 : b6;
        b0 = (b2 > b0) ? b2 : b0;
        b4 = (b6 > b4) ? b6 : b4;
        const u64 bkey = (b4 > b0) ? b4 : b0;
        const unsigned int win = ~((unsigned int)bkey);
        if (t == 0) s_cluster[step] = (int)win;

        // ---- uniform scalar fetch of winner coords ----
        const unsigned int winu =
            (unsigned int)__builtin_amdgcn_readfirstlane((int)win);
        lx = pos[winu * 3 + 0];
        ly = pos[winu * 3 + 1];
        lz = pos[winu * 3 + 2];

        // ---- exact skip test (wave-uniform; wm = own cached key's value) ----
        const u64 own = s_wkey[p][w];
        const float wm = __uint_as_float((unsigned int)(own >> 32));
        const float dm = fmaxf(fmaxf(lo - lx, lx - hi), 0.0f);
        const bool act = (dm * dm < wm);
        if (__builtin_amdgcn_readfirstlane((int)act)) UPDATE_AND_KEY();

        // ---- publish (cached or fresh) key for the NEXT step; one barrier ----
        if (lane == 63) s_wkey[p ^ 1][w] = wkey;
        __syncthreads();
    }
#undef UPDATE_AND_KEY
#undef PAIR_STAGE

    // bulk coalesced store of the cluster list
    for (int i = t; i < N_CLUSTERS; i += 1024) clusters[i] = s_cluster[i];
}

// ---------------------------------------------------------------------------
// kNN: one block per cluster, 256 threads. d = (qq+pp) - 2*dot (dot FMA-
// ascending like BLAS), LDS distance array per 8192-chunk, 16 argmin rounds
// per chunk (tie -> lower index == stable top_k), exact merge of 2x16.
// Only the neighbor SET matters downstream.
// ---------------------------------------------------------------------------
__global__ __launch_bounds__(256) void knn_kernel(const float* __restrict__ pos,
                                                  const float* __restrict__ pp,
                                                  const int* __restrict__ clusters,
                                                  int* __restrict__ nbr) {
#pragma clang fp contract(off)
    __shared__ float s_d[8192];
    __shared__ float s_rv[4];
    __shared__ int   s_ri[4];
    __shared__ float s_tv[32];
    __shared__ int   s_ti[32];
    const int m = blockIdx.x, t = threadIdx.x;
    const int lane = t & 63, w = t >> 6;

    const int qi = clusters[m];
    const float qx = pos[qi * 3 + 0], qy = pos[qi * 3 + 1], qz = pos[qi * 3 + 2];
    const float qq = ((qx * qx) + (qy * qy)) + (qz * qz);

    for (int chunk = 0; chunk < 2; ++chunk) {
        const int base = chunk << 13;
        __syncthreads();  // protect s_d overwrite vs previous chunk's reads
        for (int i = t; i < 8192; i += 256) {
            const int p = base + i;
            float dot = fmaf(qx, pos[p * 3 + 0], 0.0f);
            dot = fmaf(qy, pos[p * 3 + 1], dot);
            dot = fmaf(qz, pos[p * 3 + 2], dot);
            s_d[i] = (qq + pp[p]) - 2.0f * dot;
        }
        __syncthreads();
        for (int r = 0; r < KNN_K; ++r) {
            float bv = __builtin_inff();
            int   bi = 0x7fffffff;
            for (int i = t; i < 8192; i += 256) {   // i ascending per thread
                float v = s_d[i];
                if (v < bv) { bv = v; bi = i; }     // strict < keeps first
            }
#pragma unroll
            for (int off = 32; off >= 1; off >>= 1) {
                float ov = __shfl_down(bv, off);
                int   oi = __shfl_down(bi, off);
                if (ov < bv || (ov == bv && oi < bi)) { bv = ov; bi = oi; }
            }
            if (lane == 0) { s_rv[w] = bv; s_ri[w] = bi; }
            __syncthreads();
            if (t == 0) {
                float fv = s_rv[0]; int fi = s_ri[0];
#pragma unroll
                for (int ww = 1; ww < 4; ++ww) {
                    if (s_rv[ww] < fv || (s_rv[ww] == fv && s_ri[ww] < fi)) {
                        fv = s_rv[ww]; fi = s_ri[ww];
                    }
                }
                s_tv[chunk * 16 + r] = fv;
                s_ti[chunk * 16 + r] = base + fi;
                s_d[fi] = __builtin_inff();
            }
            __syncthreads();
        }
    }
    if (t == 0) {   // exact merge of two sorted-by-(v,idx) lists
        int a = 0, b = 0;
        for (int r = 0; r < KNN_K; ++r) {
            bool takeA;
            if (b >= 16) takeA = true;
            else if (a >= 16) takeA = false;
            else {
                float va = s_tv[a], vb = s_tv[16 + b];
                takeA = (va < vb) || (va == vb && s_ti[a] < s_ti[16 + b]);
            }
            nbr[m * KNN_K + r] = takeA ? s_ti[a] : s_ti[16 + b];
            if (takeA) ++a; else ++b;
        }
    }
}

// ---------------------------------------------------------------------------
// MLP: grouped[r] = [pos[n]-pos[r>>4] (quirky full-pos indexing!), x[n]],
// h = grouped @ W^T.  PASS 1: accumulate column sum/sumsq.  PASS 2:
// recompute, y = scale*h+shift, out[m,c] = relu(max_k y) (relu∘max=max∘relu),
// plus sub_pos / sub_batch.  64 rows (= 4 whole clusters) x 128 cols / block.
// ---------------------------------------------------------------------------
template <int PASS>
__global__ __launch_bounds__(256) void mlp_kernel(const float* __restrict__ x,
                                                  const float* __restrict__ pos,
                                                  const int* __restrict__ nbr,
                                                  const float* __restrict__ W,
                                                  float* __restrict__ colsum,
                                                  float* __restrict__ colsumsq,
                                                  const float* __restrict__ ss,
                                                  const int* __restrict__ clusters,
                                                  const int* __restrict__ batch,
                                                  float* __restrict__ out) {
    __shared__ __align__(16) float At[FAN_IN][68];     // [i][r], pad 68
    __shared__ __align__(16) float Wl[FAN_IN * 132];   // [i][c], pad 132
    __shared__ float red0[128], red1[128];
    __shared__ float hm[8][132];                       // pass2 half-cluster maxima
    const int tid = threadIdx.x;
    const int R0 = blockIdx.x * 64;

    // stage W transposed
    for (int idx = tid; idx < FAN_IN * 128; idx += 256) {
        int i = idx >> 7, c = idx & 127;
        Wl[i * 132 + c] = W[c * FAN_IN + i];
    }
    // stage A transposed (gather)
    {
        const int wv = tid >> 6, lane = tid & 63;
        for (int r = wv; r < 64; r += 4) {
            const int R = R0 + r;
            const int n = nbr[R];
            At[3 + lane][r] = x[n * C_IN + lane];
            if (lane < 3) {
                const int q = R >> 4;  // faithful to source: cluster ORDINAL indexes pos
                At[lane][r] = pos[n * 3 + lane] - pos[q * 3 + lane];
            }
        }
    }
    if (PASS == 1 && tid < 128) { red0[tid] = 0.0f; red1[tid] = 0.0f; }
    __syncthreads();

    const int g = tid & 31, rg = tid >> 5;
    const int c0 = g * 4, r0 = rg * 8;
    float acc[8][4];
#pragma unroll
    for (int a = 0; a < 8; ++a)
#pragma unroll
        for (int b = 0; b < 4; ++b) acc[a][b] = 0.0f;

    for (int i = 0; i < FAN_IN; ++i) {
        const float4 w4 = *(const float4*)&Wl[i * 132 + c0];
        const float4 a0 = *(const float4*)&At[i][r0];
        const float4 a1 = *(const float4*)&At[i][r0 + 4];
        const float av[8] = {a0.x, a0.y, a0.z, a0.w, a1.x, a1.y, a1.z, a1.w};
        const float wv4[4] = {w4.x, w4.y, w4.z, w4.w};
#pragma unroll
        for (int a = 0; a < 8; ++a)
#pragma unroll
            for (int b = 0; b < 4; ++b) acc[a][b] = fmaf(av[a], wv4[b], acc[a][b]);
    }

    if (PASS == 1) {
#pragma unroll
        for (int b = 0; b < 4; ++b) {
            float s = 0.0f, sq = 0.0f;
#pragma unroll
            for (int a = 0; a < 8; ++a) {
                s += acc[a][b];
                sq = fmaf(acc[a][b], acc[a][b], sq);
            }
            atomicAdd(&red0[c0 + b], s);
            atomicAdd(&red1[c0 + b], sq);
        }
        __syncthreads();
        if (tid < 128) {
            atomicAdd(&colsum[tid], red0[tid]);
            atomicAdd(&colsumsq[tid], red1[tid]);
        }
    } else {
        // rows r0..r0+7 lie in ONE cluster (half of it): reduce then combine
#pragma unroll
        for (int b = 0; b < 4; ++b) {
            const float sc = ss[c0 + b], sh = ss[128 + c0 + b];
            float mx = -__builtin_inff();
#pragma unroll
            for (int a = 0; a < 8; ++a) mx = fmaxf(mx, fmaf(sc, acc[a][b], sh));
            hm[rg][c0 + b] = mx;
        }
        __syncthreads();
        for (int o = tid; o < 512; o += 256) {
            const int cl = o >> 7, c = o & 127;
            const float v = fmaxf(hm[2 * cl][c], hm[2 * cl + 1][c]);
            const int M = blockIdx.x * 4 + cl;
            out[M * 128 + c] = fmaxf(v, 0.0f);
        }
        if (tid < 12) {
            const int cl = tid / 3, l = tid % 3;
            const int M = blockIdx.x * 4 + cl;
            out[524288 + M * 3 + l] = pos[clusters[M] * 3 + l];
        } else if (tid < 16) {
            const int M = blockIdx.x * 4 + (tid - 12);
            out[536576 + M] = (float)batch[clusters[M]];
        }
    }
}

// ---------------------------------------------------------------------------
// stats: scale/shift from column sums (biased var, like torch BN training)
// ---------------------------------------------------------------------------
__global__ void stats_kernel(const float* __restrict__ colsum,
                             const float* __restrict__ colsumsq,
                             const float* __restrict__ gamma,
                             const float* __restrict__ beta,
                             float* __restrict__ ss) {
    const int c = threadIdx.x;
    const float inv_n = 1.0f / (float)N_ROWS;
    const float mean = colsum[c] * inv_n;
    float var = colsumsq[c] * inv_n - mean * mean;
    var = fmaxf(var, 0.0f);
    const float inv = rsqrtf(var + 1e-5f);
    const float sc = gamma[c] * inv;
    ss[c] = sc;
    ss[128 + c] = beta[c] - mean * sc;
}

// ---------------------------------------------------------------------------
extern "C" void kernel_launch(void* const* d_in, const int* in_sizes, int n_in,
                              void* d_out, int out_size, void* d_ws, size_t ws_size,
                              hipStream_t stream) {
    const float* x     = (const float*)d_in[0];
    const float* pos   = (const float*)d_in[1];
    const int*   batch = (const int*)d_in[2];
    const float* W     = (const float*)d_in[3];
    const float* gamma = (const float*)d_in[4];
    const float* beta  = (const float*)d_in[5];
    float* out = (float*)d_out;
    float* wsf = (float*)d_ws;

    int*   clusters = (int*)d_ws;            // [4096]
    int*   nbr      = clusters + 4096;       // [65536]
    float* pp       = wsf + 69632;           // [16384]
    float* colsum   = wsf + 86016;           // [128]
    float* colsumsq = wsf + 86144;           // [128]
    float* ss       = wsf + 86272;           // [256]

    init_kernel<<<dim3(64), dim3(256), 0, stream>>>(pos, pp, colsum);
    fps_kernel<<<dim3(1), dim3(1024), 0, stream>>>(pos, clusters);
    knn_kernel<<<dim3(N_CLUSTERS), dim3(256), 0, stream>>>(pos, pp, clusters, nbr);
    mlp_kernel<1><<<dim3(1024), dim3(256), 0, stream>>>(x, pos, nbr, W, colsum, colsumsq,
                                                        ss, clusters, batch, out);
    stats_kernel<<<dim3(1), dim3(128), 0, stream>>>(colsum, colsumsq, gamma, beta, ss);
    mlp_kernel<2><<<dim3(1024), dim3(256), 0, stream>>>(x, pos, nbr, W, colsum, colsumsq,
                                                        ss, clusters, batch, out);
}

// Round 14
// 4161.390 us; speedup vs baseline: 1.7551x; 1.1160x over previous
//
#include <hip/hip_runtime.h>
#include <math.h>

#define N_PTS 16384
#define N_CLUSTERS 4096
#define KNN_K 16
#define C_IN 64
#define C_OUT 128
#define FAN_IN 67
#define N_ROWS (N_CLUSTERS * KNN_K)   // 65536
#define NBINS 256

typedef float vf2 __attribute__((ext_vector_type(2)));
typedef unsigned long long u64;

// ---------------------------------------------------------------------------
// init: pp[i] = |pos_i|^2 (reference op order, no FMA), zero colsum/colsumsq
// ---------------------------------------------------------------------------
__global__ void init_kernel(const float* __restrict__ pos, float* __restrict__ pp,
                            float* __restrict__ cz) {
#pragma clang fp contract(off)
    int i = blockIdx.x * 256 + threadIdx.x;
    if (i < N_PTS) {
        float a = pos[i * 3 + 0], b = pos[i * 3 + 1], c = pos[i * 3 + 2];
        pp[i] = ((a * a) + (b * b)) + (c * c);
    }
    if (blockIdx.x == 0 && threadIdx.x < 256) cz[threadIdx.x] = 0.0f;
}

// ---------------------------------------------------------------------------
// FPS v17 = v16 (16 waves x half-slabs, fps 4137us) + O(1)-per-wave reduce.
// v16 post-mortem: tail dominated by post-barrier ISSUE x 16 waves (each
// wave: 8x ds_read_b128 + 15-compare u64 tree ~160cyc; 4 waves/SIMD deep).
// Fix: replace the per-thread key-table scan with
//   - ONE ds_read_b64: lane reads s_wkey[p][lane&15] (16 consecutive u64 =
//     128B across all 32 banks, 4-way broadcast, conflict-free), then
//   - 4-stage DPP u64 butterfly max within each 16-lane row:
//     quad_perm[1,0,3,2] (xor1, 0xB1), quad_perm[2,3,0,1] (xor2, 0x4E),
//     row_half_mirror (0x141), row_mirror (0x140) -- all lanes valid; max is
//     associative+commutative selection => identical u64 max, bit-exact.
//   - skip test reads wm from REGISTER wkey (lane-63 readlane broadcast at
//     end of UPDATE_AND_KEY; v13-proven neutral) -> own-key LDS read gone.
// Per-wave post-barrier cost: 8 LDS + ~60 VALU  ->  1 LDS + ~25 VALU.
// All other v16/v10 machinery unchanged (x-slab ticketed partition, exact
// slab skip with monotone-RN identity proof, key = value<<32|~orig_idx,
// parity key table + ONE barrier, scalar winner-coord fetch, LDS cluster
// list).  Update math: d=((dx*dx)+(dy*dy))+(dz*dz), no FMA (contract off),
// fmin/fmax/select only -> bit-exact winner sequence vs reference.
// ---------------------------------------------------------------------------
__global__ __launch_bounds__(1024)
__attribute__((amdgpu_waves_per_eu(4, 4)))
void fps_kernel(const float* __restrict__ pos, int* __restrict__ clusters) {
#pragma clang fp contract(off)
    __shared__ unsigned short s_perm[N_PTS];     // 32KB: slot -> original index
    __shared__ int s_cluster[N_CLUSTERS];        // 16KB result accumulator
    __shared__ int s_hist[NBINS];                // histogram -> ticket base
    __shared__ float s_red[32];                  // setup reduce scratch (16 waves x2)
    __shared__ __align__(16) u64 s_wkey[2][16];  // parity-buffered wave keys
    const int t = threadIdx.x;
    const int w = t >> 6, lane = t & 63;
    const int wbase = w << 10;                   // wave owns slots [w*1024,+1024)

    // ---- setup pass 0: global x min/max ----
    float txmin = __builtin_inff(), txmax = -__builtin_inff();
#pragma unroll
    for (int k = 0; k < 16; ++k) {
        const float xv = pos[(t + (k << 10)) * 3];
        txmin = fminf(txmin, xv);
        txmax = fmaxf(txmax, xv);
    }
#pragma unroll
    for (int off = 32; off >= 1; off >>= 1) {
        txmin = fminf(txmin, __shfl_xor(txmin, off));
        txmax = fmaxf(txmax, __shfl_xor(txmax, off));
    }
    if (lane == 0) { s_red[w] = txmin; s_red[16 + w] = txmax; }
    if (t < NBINS) s_hist[t] = 0;
    if (t == 0) s_cluster[0] = 0;
    __syncthreads();
    float gxmin = s_red[0], gxmax = s_red[16];
#pragma unroll
    for (int i = 1; i < 16; ++i) {
        gxmin = fminf(gxmin, s_red[i]);
        gxmax = fmaxf(gxmax, s_red[16 + i]);
    }
    const float binv = (float)NBINS / (gxmax - gxmin);

    // ---- setup pass 1: histogram ----
#pragma unroll
    for (int k = 0; k < 16; ++k) {
        const int i = t + (k << 10);
        int b = (int)((pos[i * 3] - gxmin) * binv);
        b = (b < 0) ? 0 : ((b > NBINS - 1) ? NBINS - 1 : b);
        atomicAdd(&s_hist[b], 1);
    }
    __syncthreads();
    if (t == 0) {   // serial prefix sum (one-time)
        int run = 0;
        for (int b = 0; b < NBINS; ++b) {
            const int c = s_hist[b];
            s_hist[b] = run;
            run += c;
        }
    }
    __syncthreads();
    // ---- setup pass 2: placement (bijective by tickets) ----
#pragma unroll
    for (int k = 0; k < 16; ++k) {
        const int i = t + (k << 10);
        int b = (int)((pos[i * 3] - gxmin) * binv);
        b = (b < 0) ? 0 : ((b > NBINS - 1) ? NBINS - 1 : b);
        const int dest = atomicAdd(&s_hist[b], 1);
        s_perm[dest] = (unsigned short)i;
    }
    __syncthreads();

    // ---- gather coords + packed original indices + exact wave x-interval ----
    vf2 ax[8], ay[8], az[8], mdv[8];
    unsigned int oid[8];
    float mnx = __builtin_inff(), mxx = -__builtin_inff();
#pragma unroll
    for (int a = 0; a < 8; ++a) {
        const int s0 = wbase + (((a << 1) | 0) << 6) + lane;
        const int s1 = wbase + (((a << 1) | 1) << 6) + lane;
        const unsigned int o0 = s_perm[s0], o1 = s_perm[s1];
        oid[a] = (o1 << 16) | o0;
        ax[a] = (vf2){pos[o0 * 3 + 0], pos[o1 * 3 + 0]};
        ay[a] = (vf2){pos[o0 * 3 + 1], pos[o1 * 3 + 1]};
        az[a] = (vf2){pos[o0 * 3 + 2], pos[o1 * 3 + 2]};
        mdv[a] = (vf2){__builtin_inff(), __builtin_inff()};
        mnx = fminf(mnx, fminf(ax[a].x, ax[a].y));
        mxx = fmaxf(mxx, fmaxf(ax[a].x, ax[a].y));
    }
#pragma unroll
    for (int off = 32; off >= 1; off >>= 1) {
        mnx = fminf(mnx, __shfl_xor(mnx, off));
        mxx = fmaxf(mxx, __shfl_xor(mxx, off));
    }
    if (lane == 0) { s_red[w] = mnx; s_red[16 + w] = mxx; }
    __syncthreads();
    const float lo = s_red[w], hi = s_red[16 + w];

    float lx = pos[0], ly = pos[1], lz = pos[2];
    u64 wkey = 0;   // ALL lanes: wave's current key (readlane-broadcast)

// DPP pair-max on (hi_,lo_) u64 key; old=0 masked lanes never win (lo_!=0).
#define PAIR_STAGE(CTRL, RM)                                                          \
    do {                                                                              \
        unsigned int ohi = (unsigned int)__builtin_amdgcn_update_dpp(                 \
            0, (int)hi_, (CTRL), (RM), 0xF, false);                                   \
        unsigned int olo = (unsigned int)__builtin_amdgcn_update_dpp(                 \
            0, (int)lo_, (CTRL), (RM), 0xF, false);                                   \
        u64 cur = ((u64)hi_ << 32) | lo_;                                             \
        u64 oth = ((u64)ohi << 32) | olo;                                             \
        if (oth > cur) { hi_ = ohi; lo_ = olo; }                                      \
    } while (0)

// butterfly stage on u64 e within 16-lane rows (all lanes valid patterns)
#define BFLY_STAGE(CTRL)                                                              \
    do {                                                                              \
        unsigned int ehi = (unsigned int)(e >> 32), elo = (unsigned int)e;            \
        unsigned int ohi = (unsigned int)__builtin_amdgcn_update_dpp(                 \
            0, (int)ehi, (CTRL), 0xF, 0xF, false);                                    \
        unsigned int olo = (unsigned int)__builtin_amdgcn_update_dpp(                 \
            0, (int)elo, (CTRL), 0xF, 0xF, false);                                    \
        const u64 o = ((u64)ohi << 32) | olo;                                         \
        e = (o > e) ? o : e;                                                          \
    } while (0)

// active-wave body: packed update + min-orig-idx recovery + DPP -> wkey,
// then lane-63 readlane broadcast so every lane carries the wave key.
#define UPDATE_AND_KEY()                                                              \
    do {                                                                              \
        const vf2 lxv = (vf2){lx, lx}, lyv = (vf2){ly, ly}, lzv = (vf2){lz, lz};      \
        vf2 bm = (vf2){0.0f, 0.0f};                                                   \
        _Pragma("unroll")                                                             \
        for (int a = 0; a < 8; ++a) {                                                 \
            vf2 dx = ax[a] - lxv;                                                     \
            vf2 dy = ay[a] - lyv;                                                     \
            vf2 dz = az[a] - lzv;                                                     \
            vf2 d = ((dx * dx) + (dy * dy)) + (dz * dz);                              \
            vf2 m;                                                                    \
            m.x = fminf(mdv[a].x, d.x);                                               \
            m.y = fminf(mdv[a].y, d.y);                                               \
            mdv[a] = m;                                                               \
            bm = __builtin_elementwise_max(bm, m);                                    \
        }                                                                             \
        const float bv = fmaxf(bm.x, bm.y);                                           \
        unsigned int mi = 0xffffffffu;                                                \
        _Pragma("unroll")                                                             \
        for (int a = 0; a < 8; ++a) {                                                 \
            const unsigned int c0 =                                                   \
                (mdv[a].x == bv) ? (oid[a] & 0xffffu) : 0xffffffffu;                  \
            const unsigned int c1 =                                                   \
                (mdv[a].y == bv) ? (oid[a] >> 16) : 0xffffffffu;                      \
            const unsigned int cc = (c0 < c1) ? c0 : c1;                              \
            mi = (cc < mi) ? cc : mi;                                                 \
        }                                                                             \
        unsigned int hi_ = __float_as_uint(bv);                                       \
        unsigned int lo_ = ~mi;                                                       \
        PAIR_STAGE(0x111, 0xF);                                                       \
        PAIR_STAGE(0x112, 0xF);                                                       \
        PAIR_STAGE(0x114, 0xF);                                                       \
        PAIR_STAGE(0x118, 0xF);                                                       \
        PAIR_STAGE(0x142, 0xA);                                                       \
        PAIR_STAGE(0x143, 0xC);                                                       \
        hi_ = (unsigned int)__builtin_amdgcn_readlane((int)hi_, 63);                  \
        lo_ = (unsigned int)__builtin_amdgcn_readlane((int)lo_, 63);                  \
        wkey = ((u64)hi_ << 32) | lo_;                                                \
    } while (0)

    // ---- prologue: step-0 update vs cluster 0, publish keys to buf[1] ----
    UPDATE_AND_KEY();
    if (lane == 63) s_wkey[1][w] = wkey;
    __syncthreads();

    for (int step = 1; step < N_CLUSTERS; ++step) {
        const int p = step & 1;
        // ---- O(1)-per-wave block reduce: 1 ds_read_b64 + 4 DPP stages ----
        u64 e = s_wkey[p][lane & 15];
        BFLY_STAGE(0xB1);   // quad_perm [1,0,3,2]  (xor 1)
        BFLY_STAGE(0x4E);   // quad_perm [2,3,0,1]  (xor 2)
        BFLY_STAGE(0x141);  // row_half_mirror      (combines 4 -> 8)
        BFLY_STAGE(0x140);  // row_mirror           (combines 8 -> 16)
        const unsigned int win = ~((unsigned int)e);
        if (t == 0) s_cluster[step] = (int)win;

        // ---- uniform scalar fetch of winner coords ----
        const unsigned int winu =
            (unsigned int)__builtin_amdgcn_readfirstlane((int)win);
        lx = pos[winu * 3 + 0];
        ly = pos[winu * 3 + 1];
        lz = pos[winu * 3 + 2];

        // ---- exact skip test (wm from REGISTER wkey, no LDS read) ----
        const float wm = __uint_as_float((unsigned int)(wkey >> 32));
        const float dm = fmaxf(fmaxf(lo - lx, lx - hi), 0.0f);
        const bool act = (dm * dm < wm);
        if (__builtin_amdgcn_readfirstlane((int)act)) UPDATE_AND_KEY();

        // ---- publish (cached or fresh) key for the NEXT step; one barrier ----
        if (lane == 63) s_wkey[p ^ 1][w] = wkey;
        __syncthreads();
    }
#undef UPDATE_AND_KEY
#undef PAIR_STAGE
#undef BFLY_STAGE

    // bulk coalesced store of the cluster list
    for (int i = t; i < N_CLUSTERS; i += 1024) clusters[i] = s_cluster[i];
}

// ---------------------------------------------------------------------------
// kNN: one block per cluster, 256 threads. d = (qq+pp) - 2*dot (dot FMA-
// ascending like BLAS), LDS distance array per 8192-chunk, 16 argmin rounds
// per chunk (tie -> lower index == stable top_k), exact merge of 2x16.
// Only the neighbor SET matters downstream.
// ---------------------------------------------------------------------------
__global__ __launch_bounds__(256) void knn_kernel(const float* __restrict__ pos,
                                                  const float* __restrict__ pp,
                                                  const int* __restrict__ clusters,
                                                  int* __restrict__ nbr) {
#pragma clang fp contract(off)
    __shared__ float s_d[8192];
    __shared__ float s_rv[4];
    __shared__ int   s_ri[4];
    __shared__ float s_tv[32];
    __shared__ int   s_ti[32];
    const int m = blockIdx.x, t = threadIdx.x;
    const int lane = t & 63, w = t >> 6;

    const int qi = clusters[m];
    const float qx = pos[qi * 3 + 0], qy = pos[qi * 3 + 1], qz = pos[qi * 3 + 2];
    const float qq = ((qx * qx) + (qy * qy)) + (qz * qz);

    for (int chunk = 0; chunk < 2; ++chunk) {
        const int base = chunk << 13;
        __syncthreads();  // protect s_d overwrite vs previous chunk's reads
        for (int i = t; i < 8192; i += 256) {
            const int p = base + i;
            float dot = fmaf(qx, pos[p * 3 + 0], 0.0f);
            dot = fmaf(qy, pos[p * 3 + 1], dot);
            dot = fmaf(qz, pos[p * 3 + 2], dot);
            s_d[i] = (qq + pp[p]) - 2.0f * dot;
        }
        __syncthreads();
        for (int r = 0; r < KNN_K; ++r) {
            float bv = __builtin_inff();
            int   bi = 0x7fffffff;
            for (int i = t; i < 8192; i += 256) {   // i ascending per thread
                float v = s_d[i];
                if (v < bv) { bv = v; bi = i; }     // strict < keeps first
            }
#pragma unroll
            for (int off = 32; off >= 1; off >>= 1) {
                float ov = __shfl_down(bv, off);
                int   oi = __shfl_down(bi, off);
                if (ov < bv || (ov == bv && oi < bi)) { bv = ov; bi = oi; }
            }
            if (lane == 0) { s_rv[w] = bv; s_ri[w] = bi; }
            __syncthreads();
            if (t == 0) {
                float fv = s_rv[0]; int fi = s_ri[0];
#pragma unroll
                for (int ww = 1; ww < 4; ++ww) {
                    if (s_rv[ww] < fv || (s_rv[ww] == fv && s_ri[ww] < fi)) {
                        fv = s_rv[ww]; fi = s_ri[ww];
                    }
                }
                s_tv[chunk * 16 + r] = fv;
                s_ti[chunk * 16 + r] = base + fi;
                s_d[fi] = __builtin_inff();
            }
            __syncthreads();
        }
    }
    if (t == 0) {   // exact merge of two sorted-by-(v,idx) lists
        int a = 0, b = 0;
        for (int r = 0; r < KNN_K; ++r) {
            bool takeA;
            if (b >= 16) takeA = true;
            else if (a >= 16) takeA = false;
            else {
                float va = s_tv[a], vb = s_tv[16 + b];
                takeA = (va < vb) || (va == vb && s_ti[a] < s_ti[16 + b]);
            }
            nbr[m * KNN_K + r] = takeA ? s_ti[a] : s_ti[16 + b];
            if (takeA) ++a; else ++b;
        }
    }
}

// ---------------------------------------------------------------------------
// MLP: grouped[r] = [pos[n]-pos[r>>4] (quirky full-pos indexing!), x[n]],
// h = grouped @ W^T.  PASS 1: accumulate column sum/sumsq.  PASS 2:
// recompute, y = scale*h+shift, out[m,c] = relu(max_k y) (relu∘max=max∘relu),
// plus sub_pos / sub_batch.  64 rows (= 4 whole clusters) x 128 cols / block.
// ---------------------------------------------------------------------------
template <int PASS>
__global__ __launch_bounds__(256) void mlp_kernel(const float* __restrict__ x,
                                                  const float* __restrict__ pos,
                                                  const int* __restrict__ nbr,
                                                  const float* __restrict__ W,
                                                  float* __restrict__ colsum,
                                                  float* __restrict__ colsumsq,
                                                  const float* __restrict__ ss,
                                                  const int* __restrict__ clusters,
                                                  const int* __restrict__ batch,
                                                  float* __restrict__ out) {
    __shared__ __align__(16) float At[FAN_IN][68];     // [i][r], pad 68
    __shared__ __align__(16) float Wl[FAN_IN * 132];   // [i][c], pad 132
    __shared__ float red0[128], red1[128];
    __shared__ float hm[8][132];                       // pass2 half-cluster maxima
    const int tid = threadIdx.x;
    const int R0 = blockIdx.x * 64;

    // stage W transposed
    for (int idx = tid; idx < FAN_IN * 128; idx += 256) {
        int i = idx >> 7, c = idx & 127;
        Wl[i * 132 + c] = W[c * FAN_IN + i];
    }
    // stage A transposed (gather)
    {
        const int wv = tid >> 6, lane = tid & 63;
        for (int r = wv; r < 64; r += 4) {
            const int R = R0 + r;
            const int n = nbr[R];
            At[3 + lane][r] = x[n * C_IN + lane];
            if (lane < 3) {
                const int q = R >> 4;  // faithful to source: cluster ORDINAL indexes pos
                At[lane][r] = pos[n * 3 + lane] - pos[q * 3 + lane];
            }
        }
    }
    if (PASS == 1 && tid < 128) { red0[tid] = 0.0f; red1[tid] = 0.0f; }
    __syncthreads();

    const int g = tid & 31, rg = tid >> 5;
    const int c0 = g * 4, r0 = rg * 8;
    float acc[8][4];
#pragma unroll
    for (int a = 0; a < 8; ++a)
#pragma unroll
        for (int b = 0; b < 4; ++b) acc[a][b] = 0.0f;

    for (int i = 0; i < FAN_IN; ++i) {
        const float4 w4 = *(const float4*)&Wl[i * 132 + c0];
        const float4 a0 = *(const float4*)&At[i][r0];
        const float4 a1 = *(const float4*)&At[i][r0 + 4];
        const float av[8] = {a0.x, a0.y, a0.z, a0.w, a1.x, a1.y, a1.z, a1.w};
        const float wv4[4] = {w4.x, w4.y, w4.z, w4.w};
#pragma unroll
        for (int a = 0; a < 8; ++a)
#pragma unroll
            for (int b = 0; b < 4; ++b) acc[a][b] = fmaf(av[a], wv4[b], acc[a][b]);
    }

    if (PASS == 1) {
#pragma unroll
        for (int b = 0; b < 4; ++b) {
            float s = 0.0f, sq = 0.0f;
#pragma unroll
            for (int a = 0; a < 8; ++a) {
                s += acc[a][b];
                sq = fmaf(acc[a][b], acc[a][b], sq);
            }
            atomicAdd(&red0[c0 + b], s);
            atomicAdd(&red1[c0 + b], sq);
        }
        __syncthreads();
        if (tid < 128) {
            atomicAdd(&colsum[tid], red0[tid]);
            atomicAdd(&colsumsq[tid], red1[tid]);
        }
    } else {
        // rows r0..r0+7 lie in ONE cluster (half of it): reduce then combine
#pragma unroll
        for (int b = 0; b < 4; ++b) {
            const float sc = ss[c0 + b], sh = ss[128 + c0 + b];
            float mx = -__builtin_inff();
#pragma unroll
            for (int a = 0; a < 8; ++a) mx = fmaxf(mx, fmaf(sc, acc[a][b], sh));
            hm[rg][c0 + b] = mx;
        }
        __syncthreads();
        for (int o = tid; o < 512; o += 256) {
            const int cl = o >> 7, c = o & 127;
            const float v = fmaxf(hm[2 * cl][c], hm[2 * cl + 1][c]);
            const int M = blockIdx.x * 4 + cl;
            out[M * 128 + c] = fmaxf(v, 0.0f);
        }
        if (tid < 12) {
            const int cl = tid / 3, l = tid % 3;
            const int M = blockIdx.x * 4 + cl;
            out[524288 + M * 3 + l] = pos[clusters[M] * 3 + l];
        } else if (tid < 16) {
            const int M = blockIdx.x * 4 + (tid - 12);
            out[536576 + M] = (float)batch[clusters[M]];
        }
    }
}

// ---------------------------------------------------------------------------
// stats: scale/shift from column sums (biased var, like torch BN training)
// ---------------------------------------------------------------------------
__global__ void stats_kernel(const float* __restrict__ colsum,
                             const float* __restrict__ colsumsq,
                             const float* __restrict__ gamma,
                             const float* __restrict__ beta,
                             float* __restrict__ ss) {
    const int c = threadIdx.x;
    const float inv_n = 1.0f / (float)N_ROWS;
    const float mean = colsum[c] * inv_n;
    float var = colsumsq[c] * inv_n - mean * mean;
    var = fmaxf(var, 0.0f);
    const float inv = rsqrtf(var + 1e-5f);
    const float sc = gamma[c] * inv;
    ss[c] = sc;
    ss[128 + c] = beta[c] - mean * sc;
}

// ---------------------------------------------------------------------------
extern "C" void kernel_launch(void* const* d_in, const int* in_sizes, int n_in,
                              void* d_out, int out_size, void* d_ws, size_t ws_size,
                              hipStream_t stream) {
    const float* x     = (const float*)d_in[0];
    const float* pos   = (const float*)d_in[1];
    const int*   batch = (const int*)d_in[2];
    const float* W     = (const float*)d_in[3];
    const float* gamma = (const float*)d_in[4];
    const float* beta  = (const float*)d_in[5];
    float* out = (float*)d_out;
    float* wsf = (float*)d_ws;

    int*   clusters = (int*)d_ws;            // [4096]
    int*   nbr      = clusters + 4096;       // [65536]
    float* pp       = wsf + 69632;           // [16384]
    float* colsum   = wsf + 86016;           // [128]
    float* colsumsq = wsf + 86144;           // [128]
    float* ss       = wsf + 86272;           // [256]

    init_kernel<<<dim3(64), dim3(256), 0, stream>>>(pos, pp, colsum);
    fps_kernel<<<dim3(1), dim3(1024), 0, stream>>>(pos, clusters);
    knn_kernel<<<dim3(N_CLUSTERS), dim3(256), 0, stream>>>(pos, pp, clusters, nbr);
    mlp_kernel<1><<<dim3(1024), dim3(256), 0, stream>>>(x, pos, nbr, W, colsum, colsumsq,
                                                        ss, clusters, batch, out);
    stats_kernel<<<dim3(1), dim3(128), 0, stream>>>(colsum, colsumsq, gamma, beta, ss);
    mlp_kernel<2><<<dim3(1024), dim3(256), 0, stream>>>(x, pos, nbr, W, colsum, colsumsq,
                                                        ss, clusters, batch, out);
}